// Round 5
// baseline (585.927 us; speedup 1.0000x reference)
//
#include <hip/hip_runtime.h>
#include <hip/hip_bf16.h>

// Problem constants
#define H_    16
#define NOPE_ 128
#define ROPE_ 64
#define VDIM_ 128
#define LORA_ 512
#define DM_   2048
#define T_    256
#define S_    32768
#define K_    2048

static constexpr float SCALE_ = 0.072168783648703220563643597562744f; // 1/sqrt(192)
static constexpr float LOG2E_ = 1.4426950408889634f;

typedef __attribute__((ext_vector_type(8))) short short8;   // 8 bf16 in 4 VGPRs
typedef __attribute__((ext_vector_type(4))) short short4v;  // 4 bf16 in 2 VGPRs
typedef __attribute__((ext_vector_type(4))) float f32x4;    // MFMA accumulator

__device__ __forceinline__ ushort f2bf(float f) {
    unsigned u = __float_as_uint(f);
    unsigned r = (u + 0x7FFFu + ((u >> 16) & 1u)) >> 16;    // RNE
    return (ushort)r;
}
__device__ __forceinline__ float bf2f(ushort u) {
    return __uint_as_float((unsigned)u << 16);
}

// ---------------------------------------------------------------------------
// bf16 MFMA GEMM: C[M,N] = A[M,K] @ B[K,N] (B_NT: B is [N][K] n-major).
// BM=BN=64, BK=64, 256 thr (4 waves, each a 32x32 quadrant, 2x2 MFMA tiles).
// ---------------------------------------------------------------------------
template<bool A_BF16, bool B_NT, bool C_BF16>
__global__ __launch_bounds__(256) void gemm_mfma(
    const void* __restrict__ Av, const float* __restrict__ B, void* __restrict__ Cv,
    int M, int N, int Kd, int lda, int ldb, int ldc,
    long batchA, long batchB, long batchC)
{
    __shared__ ushort As[64 * 72];
    __shared__ ushort Bs[64 * 72];

    const int tid = threadIdx.x;
    const int w  = tid >> 6;
    const int l  = tid & 63;
    const int lm = l & 15;
    const int kq = l >> 4;
    const int bm = blockIdx.y * 64;
    const int bn = blockIdx.x * 64;
    const int m0 = (w >> 1) * 32;
    const int n0 = (w & 1) * 32;

    const float*  Af = A_BF16 ? nullptr : ((const float*)Av)  + (long)blockIdx.z * batchA;
    const ushort* Ah = A_BF16 ? ((const ushort*)Av) + (long)blockIdx.z * batchA : nullptr;
    B += (long)blockIdx.z * batchB;

    f32x4 acc[2][2];
    #pragma unroll
    for (int i = 0; i < 2; ++i)
        #pragma unroll
        for (int j = 0; j < 2; ++j) acc[i][j] = (f32x4){0.f, 0.f, 0.f, 0.f};

    for (int k0 = 0; k0 < Kd; k0 += 64) {
        __syncthreads();
        // ---- stage A -> As[m][k] bf16 ----
        if constexpr (A_BF16) {
            int m = tid >> 2, ko = (tid & 3) * 16;
            const ushort* src = Ah + (long)(bm + m) * lda + k0 + ko;
            *(uint4*)(As + m * 72 + ko)     = *(const uint4*)(src);
            *(uint4*)(As + m * 72 + ko + 8) = *(const uint4*)(src + 8);
        } else {
            int mr = tid >> 4, kk = (tid & 15) * 4;
            #pragma unroll
            for (int p = 0; p < 4; ++p) {
                int m = mr + p * 16;
                float4 v = *(const float4*)(Af + (long)(bm + m) * lda + k0 + kk);
                ushort4 u;
                u.x = f2bf(v.x); u.y = f2bf(v.y); u.z = f2bf(v.z); u.w = f2bf(v.w);
                *(ushort4*)(As + m * 72 + kk) = u;
            }
        }
        // ---- stage B ----
        if constexpr (B_NT) {
            int nr = tid >> 4, kk = (tid & 15) * 4;
            #pragma unroll
            for (int p = 0; p < 4; ++p) {
                int n = nr + p * 16;
                float4 v = *(const float4*)(B + (long)(bn + n) * ldb + k0 + kk);
                ushort4 u;
                u.x = f2bf(v.x); u.y = f2bf(v.y); u.z = f2bf(v.z); u.w = f2bf(v.w);
                *(ushort4*)(Bs + n * 72 + kk) = u;
            }
        } else {
            int k = tid >> 2, nq = (tid & 3) * 16;
            #pragma unroll
            for (int p = 0; p < 4; ++p) {
                float4 v = *(const float4*)(B + (long)(k0 + k) * ldb + bn + nq + p * 4);
                ushort4 u;
                u.x = f2bf(v.x); u.y = f2bf(v.y); u.z = f2bf(v.z); u.w = f2bf(v.w);
                *(ushort4*)(Bs + k * 68 + nq + p * 4) = u;
            }
        }
        __syncthreads();
        // ---- compute: 2 k-steps of 32 ----
        #pragma unroll
        for (int ks = 0; ks < 2; ++ks) {
            short8 a[2], b[2];
            #pragma unroll
            for (int mt = 0; mt < 2; ++mt)
                a[mt] = *(const short8*)(As + (m0 + mt * 16 + lm) * 72 + ks * 32 + kq * 8);
            if constexpr (B_NT) {
                #pragma unroll
                for (int nt = 0; nt < 2; ++nt)
                    b[nt] = *(const short8*)(Bs + (n0 + nt * 16 + lm) * 72 + ks * 32 + kq * 8);
            } else {
                #pragma unroll
                for (int nt = 0; nt < 2; ++nt)
                    #pragma unroll
                    for (int j = 0; j < 8; ++j)
                        b[nt][j] = (short)Bs[(ks * 32 + kq * 8 + j) * 68 + n0 + nt * 16 + lm];
            }
            #pragma unroll
            for (int mt = 0; mt < 2; ++mt)
                #pragma unroll
                for (int nt = 0; nt < 2; ++nt)
                    acc[mt][nt] = __builtin_amdgcn_mfma_f32_16x16x32_bf16(
                        a[mt], b[nt], acc[mt][nt], 0, 0, 0);
        }
    }
    // ---- epilogue ----
    #pragma unroll
    for (int mt = 0; mt < 2; ++mt)
        #pragma unroll
        for (int nt = 0; nt < 2; ++nt)
            #pragma unroll
            for (int r = 0; r < 4; ++r) {
                long row = bm + m0 + mt * 16 + kq * 4 + r;
                long col = bn + n0 + nt * 16 + lm;
                if constexpr (C_BF16)
                    ((ushort*)Cv)[(long)blockIdx.z * batchC + row * ldc + col] =
                        f2bf(acc[mt][nt][r]);
                else
                    ((float*)Cv)[(long)blockIdx.z * batchC + row * ldc + col] =
                        acc[mt][nt][r];
            }
}

// ---------------------------------------------------------------------------
// qb[:, :, 512:576] = bf16(rope(q_pe)) from fp32 qfull. fp64 angles.
// ---------------------------------------------------------------------------
__global__ __launch_bounds__(256) void pack_qrope(
    const float* __restrict__ qfull, const int* __restrict__ pos_q,
    ushort* __restrict__ qb)
{
    int id = blockIdx.x * 256 + threadIdx.x;     // T*H*32 = 131072
    int i = id & 31;
    int h = (id >> 5) & 15;
    int t = id >> 9;
    double inv = exp2(-(double)i * 0.41524101186092026);  // 10000^(-i/32)
    double f = (double)pos_q[t] * inv;
    double fr = f - floor(f * 0.15915494309189535) * 6.283185307179586;
    float sf, cf;
    sincosf((float)fr, &sf, &cf);
    float x1 = qfull[t * 3072 + h * 192 + 128 + i];
    float x2 = qfull[t * 3072 + h * 192 + 160 + i];
    ushort* q = qb + (long)(t * 16 + h) * 576;
    q[512 + i] = f2bf(x1 * cf - x2 * sf);
    q[544 + i] = f2bf(x2 * cf + x1 * sf);
}

// ---------------------------------------------------------------------------
// Precompute kvb[s][0:512]=bf16(kv_c[s]), kvb[s][512:576]=bf16(rope(k_pe[s],s)).
// (round-0 HW-verified form; 72 lanes/row)
// ---------------------------------------------------------------------------
__global__ __launch_bounds__(256) void prep_kvb(
    const float* __restrict__ kvc, const float* __restrict__ kpe,
    ushort* __restrict__ kvb)
{
    int id = blockIdx.x * 256 + threadIdx.x;   // 32768*72 = 2,359,296
    int s = id / 72;
    int c = id - s * 72;
    if (c < 64) {
        const float* src = kvc + (long)s * 512 + c * 8;
        float4 v0 = *(const float4*)src;
        float4 v1 = *(const float4*)(src + 4);
        ushort4 a, b;
        a.x = f2bf(v0.x); a.y = f2bf(v0.y); a.z = f2bf(v0.z); a.w = f2bf(v0.w);
        b.x = f2bf(v1.x); b.y = f2bf(v1.y); b.z = f2bf(v1.z); b.w = f2bf(v1.w);
        ushort* dst = kvb + (long)s * 576 + c * 8;
        *(ushort4*)dst = a;
        *(ushort4*)(dst + 4) = b;
    } else {
        int q = c - 64;                       // 0..7 -> rope dims q*8..q*8+7
        const float* kp = kpe + (long)s * 64;
        ushort* dst = kvb + (long)s * 576 + 512 + q * 8;
        #pragma unroll
        for (int e = 0; e < 8; ++e) {
            int d = q * 8 + e;
            int i = d & 31;
            double inv = exp2(-(double)i * 0.41524101186092026);
            double f = (double)s * inv;
            double fr = f - floor(f * 0.15915494309189535) * 6.283185307179586;
            float sf, cf;
            sincosf((float)fr, &sf, &cf);
            float x1 = kp[i], x2 = kp[32 + i];
            dst[e] = (d < 32) ? f2bf(x1 * cf - x2 * sf) : f2bf(x2 * cf + x1 * sf);
        }
    }
}

// ---------------------------------------------------------------------------
// Fused flash-MLA attention, split-K=2 (512 blocks, 2/CU).
//
// LDS key-tile layout, subtiled (bijective, HW-verified round 4):
//   off(s,d) = (d>>4)*2048 + (s>>2)*128 + (s&3)*32 + (d&15)*2
// Each 128B subtile is a 4x16 row-major [key][dim] bf16 tile.
// ds_read_b64_tr_b16 semantics (HW-verified round 4): each lane reads 8B at
// its own address; the 16-lane group's 128B are exchanged so lane l elem j =
// block elem (l&15)+16j. Address lane (l&15) -> tile_base + (l&15)*8.
//
// Round-5 schedule changes (addressing identical to the PASSING round-4):
//  - PV software-pipelined: 4 tr reads + 2 MFMAs per vt-chunk, counted
//    lgkmcnt(8) waits keep >=8 reads in flight under MFMA (round-4's
//    monolithic 40-read batch + lgkmcnt(0) drain serialized LDS vs MFMA
//    pipes -> 122.9us vs round-0's 98us).
//  - T14 gather prefetch: next tile's 18 global_load_dwordx4 issued into
//    registers right after the current ds_writes; they land during
//    QK+softmax+PV instead of stalling all waves at the tile top.
//  - QK dependent MFMA chain split into S0/S1.
// ---------------------------------------------------------------------------
#define KBD 2048    // d-block pitch in bytes (16 subtiles * 128B, dense)

__global__ __launch_bounds__(256, 2) void mla_fused_split(
    const ushort* __restrict__ qb, const ushort* __restrict__ kvb,
    const int* __restrict__ topk,
    ushort* __restrict__ Opart, float* __restrict__ ml)
{
    __shared__ __align__(16) char kb[36 * KBD];   // 73,728 B
    __shared__ __align__(16) ushort P2[1024];     // P, key-subtiled (2 KiB)
    __shared__ float wred[2][4][16];              // [max|sum][wave][row]

    const int t = blockIdx.x;
    const int sp = blockIdx.y;          // split 0/1
    const int tid = threadIdx.x;
    const int w = tid >> 6;
    const int l = tid & 63;
    const int lm = l & 15;
    const int kq = l >> 4;

    // ---- preload Q A-fragments (18 k-steps of 32) ----
    short8 qa[18];
    {
        const ushort* qrow = qb + (long)(t * 16 + lm) * 576 + kq * 8;
        #pragma unroll
        for (int ks = 0; ks < 18; ++ks)
            qa[ks] = *(const short8*)(qrow + ks * 32);
    }

    const int skk = tid >> 2;        // staging: key row 0..63
    const int sq = tid & 3;          // quarter (16B chunk of 64B span)
    const int* tkp = topk + (long)t * 2048 + sp * 1024;

    // staging dst base: key skk, dim chunk d = sq*8 (+32 per i -> +2 d-blocks)
    char* sdst = kb + (sq >> 1) * KBD + (skk >> 2) * 128
               + (skk & 3) * 32 + (sq & 1) * 16;

    // QK B-fragment base: key = w*16+lm, dim = ks*32 + kq*8
    const char* krow = kb + (kq >> 1) * KBD + w * 512 + (lm >> 2) * 128
                     + (lm & 3) * 32 + (kq & 1) * 16;

    // PV tr-read bases: lane lm owns the lm-th 8-byte chunk of each 4x16 tile
    const unsigned trbase = (unsigned)(unsigned long long)(const void*)kb
                          + (unsigned)(w * 8 * KBD + kq * 256 + lm * 8);
    const unsigned ptrb = (unsigned)(unsigned long long)(const void*)P2
                        + (unsigned)(kq * 256 + lm * 8);

    f32x4 O[8];
    #pragma unroll
    for (int vt = 0; vt < 8; ++vt) O[vt] = (f32x4){0.f, 0.f, 0.f, 0.f};
    float m_r[4] = {-1e30f, -1e30f, -1e30f, -1e30f};
    float l_r[4] = {0.f, 0.f, 0.f, 0.f};

    // ---- T14 prefetch: tile 0 gather -> registers ----
    uint4 g[18];
    {
        int idx = tkp[skk];
        const ushort* src = kvb + (long)idx * 576 + sq * 8;
        #pragma unroll
        for (int i = 0; i < 18; ++i)
            g[i] = *(const uint4*)(src + i * 32);
    }

    for (int kt = 0; kt < 1024; kt += 64) {
        __syncthreads();   // kb consumable (prev tile's reads done)
        // ---- write prefetched tile into subtiled LDS ----
        #pragma unroll
        for (int i = 0; i < 18; ++i)
            *(uint4*)(sdst + i * (2 * KBD)) = g[i];
        // ---- issue next tile's gather (lands during compute) ----
        if (kt + 64 < 1024) {
            int idx = tkp[kt + 64 + skk];
            const ushort* src = kvb + (long)idx * 576 + sq * 8;
            #pragma unroll
            for (int i = 0; i < 18; ++i)
                g[i] = *(const uint4*)(src + i * 32);
        }
        __syncthreads();   // kb ready

        // ---- S = Q . K^T for this wave's 16 keys (2 chains) ----
        f32x4 S0 = (f32x4){0.f, 0.f, 0.f, 0.f};
        f32x4 S1 = (f32x4){0.f, 0.f, 0.f, 0.f};
        #pragma unroll
        for (int ks = 0; ks < 18; ks += 2) {
            short8 b0 = *(const short8*)(krow + ks * (2 * KBD));
            S0 = __builtin_amdgcn_mfma_f32_16x16x32_bf16(qa[ks], b0, S0, 0, 0, 0);
            short8 b1 = *(const short8*)(krow + (ks + 1) * (2 * KBD));
            S1 = __builtin_amdgcn_mfma_f32_16x16x32_bf16(qa[ks + 1], b1, S1, 0, 0, 0);
        }
        float s4[4], mx[4], p[4];
        #pragma unroll
        for (int r = 0; r < 4; ++r) { s4[r] = (S0[r] + S1[r]) * SCALE_; mx[r] = s4[r]; }
        #pragma unroll
        for (int off = 1; off < 16; off <<= 1)
            #pragma unroll
            for (int r = 0; r < 4; ++r)
                mx[r] = fmaxf(mx[r], __shfl_xor(mx[r], off, 64));
        if (lm == 0)
            #pragma unroll
            for (int r = 0; r < 4; ++r) wred[0][w][4 * kq + r] = mx[r];
        __syncthreads();

        float al[4], rs[4];
        #pragma unroll
        for (int r = 0; r < 4; ++r) {
            float tm = fmaxf(fmaxf(wred[0][0][4 * kq + r], wred[0][1][4 * kq + r]),
                             fmaxf(wred[0][2][4 * kq + r], wred[0][3][4 * kq + r]));
            float mn = fmaxf(m_r[r], tm);
            al[r] = exp2f((m_r[r] - mn) * LOG2E_);
            p[r] = exp2f((s4[r] - mn) * LOG2E_);
            m_r[r] = mn;
            rs[r] = p[r];
        }
        #pragma unroll
        for (int off = 1; off < 16; off <<= 1)
            #pragma unroll
            for (int r = 0; r < 4; ++r)
                rs[r] += __shfl_xor(rs[r], off, 64);
        if (lm == 0)
            #pragma unroll
            for (int r = 0; r < 4; ++r) wred[1][w][4 * kq + r] = rs[r];
        // P write: key = w*16+lm, heads 4kq..4kq+3 consecutive -> one b64 store
        {
            ushort4 pu;
            pu.x = f2bf(p[0]); pu.y = f2bf(p[1]);
            pu.z = f2bf(p[2]); pu.w = f2bf(p[3]);
            *(ushort4*)(P2 + (w * 4 + (lm >> 2)) * 64 + (lm & 3) * 16 + 4 * kq) = pu;
        }
        #pragma unroll
        for (int vt = 0; vt < 8; ++vt)
            #pragma unroll
            for (int r = 0; r < 4; ++r)
                O[vt][r] *= al[r];
        __syncthreads();   // P2 + wred[1] visible

        #pragma unroll
        for (int r = 0; r < 4; ++r) {
            float ts = wred[1][0][4 * kq + r] + wred[1][1][4 * kq + r] +
                       wred[1][2][4 * kq + r] + wred[1][3][4 * kq + r];
            l_r[r] = l_r[r] * al[r] + ts;
        }

        // ---- O += P . V : software-pipelined tr reads (counted lgkmcnt) ----
        // Fence: keep the wred ds_reads above the counted window.
        __builtin_amdgcn_sched_barrier(0);
        short4v pr[4];
        asm volatile("ds_read_b64_tr_b16 %0, %1 offset:0"    : "=v"(pr[0]) : "v"(ptrb));
        asm volatile("ds_read_b64_tr_b16 %0, %1 offset:128"  : "=v"(pr[1]) : "v"(ptrb));
        asm volatile("ds_read_b64_tr_b16 %0, %1 offset:1024" : "=v"(pr[2]) : "v"(ptrb));
        asm volatile("ds_read_b64_tr_b16 %0, %1 offset:1152" : "=v"(pr[3]) : "v"(ptrb));
        short4v rg[4][4];
#define ISSUE_V(vt, slot) \
        asm volatile("ds_read_b64_tr_b16 %0, %1 offset:%2" : "=v"(rg[slot][0]) : "v"(trbase), "i"((vt) * KBD));        \
        asm volatile("ds_read_b64_tr_b16 %0, %1 offset:%2" : "=v"(rg[slot][1]) : "v"(trbase), "i"((vt) * KBD + 128));  \
        asm volatile("ds_read_b64_tr_b16 %0, %1 offset:%2" : "=v"(rg[slot][2]) : "v"(trbase), "i"((vt) * KBD + 1024)); \
        asm volatile("ds_read_b64_tr_b16 %0, %1 offset:%2" : "=v"(rg[slot][3]) : "v"(trbase), "i"((vt) * KBD + 1152));
        ISSUE_V(0, 0)
        ISSUE_V(1, 1)
        asm volatile("s_waitcnt lgkmcnt(8)" ::: "memory");   // pr ready
        __builtin_amdgcn_sched_barrier(0);
        short8 pa0 = __builtin_shufflevector(pr[0], pr[1], 0, 1, 2, 3, 4, 5, 6, 7);
        short8 pa1 = __builtin_shufflevector(pr[2], pr[3], 0, 1, 2, 3, 4, 5, 6, 7);
        #pragma unroll
        for (int vt = 0; vt < 8; ++vt) {
            if (vt < 6) { ISSUE_V(vt + 2, (vt + 2) & 3) }
            if (vt < 6)
                asm volatile("s_waitcnt lgkmcnt(8)" ::: "memory");  // chunk vt ready
            else if (vt == 6)
                asm volatile("s_waitcnt lgkmcnt(4)" ::: "memory");
            else
                asm volatile("s_waitcnt lgkmcnt(0)" ::: "memory");
            __builtin_amdgcn_sched_barrier(0);
            short8 bv0 = __builtin_shufflevector(rg[vt & 3][0], rg[vt & 3][1],
                                                 0, 1, 2, 3, 4, 5, 6, 7);
            O[vt] = __builtin_amdgcn_mfma_f32_16x16x32_bf16(pa0, bv0, O[vt], 0, 0, 0);
            short8 bv1 = __builtin_shufflevector(rg[vt & 3][2], rg[vt & 3][3],
                                                 0, 1, 2, 3, 4, 5, 6, 7);
            O[vt] = __builtin_amdgcn_mfma_f32_16x16x32_bf16(pa1, bv1, O[vt], 0, 0, 0);
        }
#undef ISSUE_V
    }

    // ---- epilogue: store unnormalized partial O (bf16) + (m,l) ----
    const long rbase = ((long)sp * 256 + t) * 16;
    #pragma unroll
    for (int vt = 0; vt < 8; ++vt)
        #pragma unroll
        for (int r = 0; r < 4; ++r)
            Opart[(rbase + 4 * kq + r) * 512 + w * 128 + vt * 16 + lm] = f2bf(O[vt][r]);
    if (w == 0 && lm == 0) {
        #pragma unroll
        for (int r = 0; r < 4; ++r) {
            ml[(rbase + 4 * kq + r) * 2 + 0] = m_r[r];
            ml[(rbase + 4 * kq + r) * 2 + 1] = l_r[r];
        }
    }
}

// ---------------------------------------------------------------------------
// Merge the 2 split-K partials -> olat bf16.
// ---------------------------------------------------------------------------
__global__ __launch_bounds__(256) void combine_kernel(
    const ushort* __restrict__ Opart, const float* __restrict__ ml,
    ushort* __restrict__ olat)
{
    const int t = blockIdx.x;
    const int h = threadIdx.x >> 4;
    const int v0 = (threadIdx.x & 15) * 32;
    const long r0 = (long)t * 16 + h;
    const long r1 = (long)(256 + t) * 16 + h;
    float m0 = ml[r0 * 2], l0 = ml[r0 * 2 + 1];
    float m1 = ml[r1 * 2], l1 = ml[r1 * 2 + 1];
    float M = fmaxf(m0, m1);
    float w0 = exp2f((m0 - M) * LOG2E_);
    float w1 = exp2f((m1 - M) * LOG2E_);
    float inv = 1.0f / (w0 * l0 + w1 * l1);
    const ushort* p0 = Opart + r0 * 512 + v0;
    const ushort* p1 = Opart + r1 * 512 + v0;
    ushort* po = olat + r0 * 512 + v0;
    #pragma unroll
    for (int i = 0; i < 32; i += 4) {
        ushort4 a = *(const ushort4*)(p0 + i);
        ushort4 b = *(const ushort4*)(p1 + i);
        ushort4 o;
        o.x = f2bf((w0 * bf2f(a.x) + w1 * bf2f(b.x)) * inv);
        o.y = f2bf((w0 * bf2f(a.y) + w1 * bf2f(b.y)) * inv);
        o.z = f2bf((w0 * bf2f(a.z) + w1 * bf2f(b.z)) * inv);
        o.w = f2bf((w0 * bf2f(a.w) + w1 * bf2f(b.w)) * inv);
        *(ushort4*)(po + i) = o;
    }
}

// ---------------------------------------------------------------------------
// Launch. ws footprint exactly 54,001,664 B (proven safe in R5).
// ---------------------------------------------------------------------------
extern "C" void kernel_launch(void* const* d_in, const int* in_sizes, int n_in,
                              void* d_out, int out_size, void* d_ws, size_t ws_size,
                              hipStream_t stream)
{
    const float* x    = (const float*)d_in[0];
    const float* Wq   = (const float*)d_in[1];
    const float* W_UK = (const float*)d_in[2];
    const float* W_UV = (const float*)d_in[3];
    const float* Wo   = (const float*)d_in[4];
    const float* kv_c = (const float*)d_in[5];
    const float* k_pe = (const float*)d_in[6];
    const int* topk   = (const int*)d_in[7];
    const int* pos_q  = (const int*)d_in[8];
    float* out        = (float*)d_out;

    char* wsb = (char*)d_ws;
    ushort* qb    = (ushort*)wsb;
    float*  qfull = (float*)(wsb + 4718592);
    ushort* Opart = (ushort*)(wsb + 4718592);          // overlay of qfull
    ushort* ov_b  = (ushort*)(wsb + 13107200);
    float*  ml    = (float*)(wsb + 14155776);
    ushort* olat  = qb;                                // overlay (qb dead)
    ushort* kvb   = (ushort*)(wsb + 16252928);
    if (ws_size < (size_t)54001664) return;            // fail loud, don't fault

    // 0) prep bf16 kv table
    prep_kvb<<<9216, 256, 0, stream>>>(kv_c, k_pe, kvb);

    // 1) qfull = x @ Wq   (256 x 3072 x 2048), fp32 out
    gemm_mfma<false, false, false><<<dim3(48, 4), 256, 0, stream>>>(
        x, Wq, qfull, 256, 3072, 2048, 2048, 3072, 3072, 0, 0, 0);

    // 2) qb[:, :, 0:512] = qnope @ W_UK[h]  (256 x 512 x 128, batched over h)
    gemm_mfma<false, false, true><<<dim3(8, 4, 16), 256, 0, stream>>>(
        qfull, W_UK, qb, 256, 512, 128, 3072, 512, 9216, 192, 65536, 576);

    // 3) qb[:, :, 512:576] = bf16(rope(q_pe))
    pack_qrope<<<512, 256, 0, stream>>>(qfull, pos_q, qb);

    // 4) fused attention, split-K=2 -> partials
    mla_fused_split<<<dim3(256, 2), 256, 0, stream>>>(qb, kvb, topk, Opart, ml);

    // 5) combine partials -> olat (bf16, overlays qb)
    combine_kernel<<<256, 256, 0, stream>>>(Opart, ml, olat);

    // 6) ov_b[t, h*128+v] = olat[t,h,:] . W_UV[h,v,:]  (NT, A bf16, C bf16)
    gemm_mfma<true, true, true><<<dim3(2, 4, 16), 256, 0, stream>>>(
        olat, W_UV, ov_b, 256, 128, 512, 8192, 512, 2048, 512, 65536, 128);

    // 7) out = ov_b @ Wo   (256 x 2048 x 2048), fp32 out
    gemm_mfma<true, false, false><<<dim3(32, 4), 256, 0, stream>>>(
        ov_b, Wo, out, 256, 2048, 2048, 2048, 2048, 2048, 0, 0, 0);
}

// Round 6
// 450.801 us; speedup vs baseline: 1.2997x; 1.2997x over previous
//
#include <hip/hip_runtime.h>
#include <hip/hip_bf16.h>

// Problem constants
#define H_    16
#define NOPE_ 128
#define ROPE_ 64
#define VDIM_ 128
#define LORA_ 512
#define DM_   2048
#define T_    256
#define S_    32768
#define K_    2048

static constexpr float SCALE_ = 0.072168783648703220563643597562744f; // 1/sqrt(192)
static constexpr float LOG2E_ = 1.4426950408889634f;

typedef __attribute__((ext_vector_type(8))) short short8;   // 8 bf16 in 4 VGPRs
typedef __attribute__((ext_vector_type(4))) short short4v;  // 4 bf16 in 2 VGPRs
typedef __attribute__((ext_vector_type(4))) float f32x4;    // MFMA accumulator

__device__ __forceinline__ ushort f2bf(float f) {
    unsigned u = __float_as_uint(f);
    unsigned r = (u + 0x7FFFu + ((u >> 16) & 1u)) >> 16;    // RNE
    return (ushort)r;
}
__device__ __forceinline__ float bf2f(ushort u) {
    return __uint_as_float((unsigned)u << 16);
}

// ---------------------------------------------------------------------------
// bf16 MFMA GEMM: C[M,N] = A[M,K] @ B[K,N] (B_NT: B is [N][K] n-major).
// BM=BN=64, BK=64, 256 thr (4 waves, each a 32x32 quadrant, 2x2 MFMA tiles).
// ---------------------------------------------------------------------------
template<bool A_BF16, bool B_NT, bool C_BF16>
__global__ __launch_bounds__(256) void gemm_mfma(
    const void* __restrict__ Av, const float* __restrict__ B, void* __restrict__ Cv,
    int M, int N, int Kd, int lda, int ldb, int ldc,
    long batchA, long batchB, long batchC)
{
    __shared__ ushort As[64 * 72];
    __shared__ ushort Bs[64 * 72];

    const int tid = threadIdx.x;
    const int w  = tid >> 6;
    const int l  = tid & 63;
    const int lm = l & 15;
    const int kq = l >> 4;
    const int bm = blockIdx.y * 64;
    const int bn = blockIdx.x * 64;
    const int m0 = (w >> 1) * 32;
    const int n0 = (w & 1) * 32;

    const float*  Af = A_BF16 ? nullptr : ((const float*)Av)  + (long)blockIdx.z * batchA;
    const ushort* Ah = A_BF16 ? ((const ushort*)Av) + (long)blockIdx.z * batchA : nullptr;
    B += (long)blockIdx.z * batchB;

    f32x4 acc[2][2];
    #pragma unroll
    for (int i = 0; i < 2; ++i)
        #pragma unroll
        for (int j = 0; j < 2; ++j) acc[i][j] = (f32x4){0.f, 0.f, 0.f, 0.f};

    for (int k0 = 0; k0 < Kd; k0 += 64) {
        __syncthreads();
        // ---- stage A -> As[m][k] bf16 ----
        if constexpr (A_BF16) {
            int m = tid >> 2, ko = (tid & 3) * 16;
            const ushort* src = Ah + (long)(bm + m) * lda + k0 + ko;
            *(uint4*)(As + m * 72 + ko)     = *(const uint4*)(src);
            *(uint4*)(As + m * 72 + ko + 8) = *(const uint4*)(src + 8);
        } else {
            int mr = tid >> 4, kk = (tid & 15) * 4;
            #pragma unroll
            for (int p = 0; p < 4; ++p) {
                int m = mr + p * 16;
                float4 v = *(const float4*)(Af + (long)(bm + m) * lda + k0 + kk);
                ushort4 u;
                u.x = f2bf(v.x); u.y = f2bf(v.y); u.z = f2bf(v.z); u.w = f2bf(v.w);
                *(ushort4*)(As + m * 72 + kk) = u;
            }
        }
        // ---- stage B ----
        if constexpr (B_NT) {
            int nr = tid >> 4, kk = (tid & 15) * 4;
            #pragma unroll
            for (int p = 0; p < 4; ++p) {
                int n = nr + p * 16;
                float4 v = *(const float4*)(B + (long)(bn + n) * ldb + k0 + kk);
                ushort4 u;
                u.x = f2bf(v.x); u.y = f2bf(v.y); u.z = f2bf(v.z); u.w = f2bf(v.w);
                *(ushort4*)(Bs + n * 72 + kk) = u;
            }
        } else {
            int k = tid >> 2, nq = (tid & 3) * 16;
            #pragma unroll
            for (int p = 0; p < 4; ++p) {
                float4 v = *(const float4*)(B + (long)(k0 + k) * ldb + bn + nq + p * 4);
                ushort4 u;
                u.x = f2bf(v.x); u.y = f2bf(v.y); u.z = f2bf(v.z); u.w = f2bf(v.w);
                *(ushort4*)(Bs + k * 68 + nq + p * 4) = u;
            }
        }
        __syncthreads();
        // ---- compute: 2 k-steps of 32 ----
        #pragma unroll
        for (int ks = 0; ks < 2; ++ks) {
            short8 a[2], b[2];
            #pragma unroll
            for (int mt = 0; mt < 2; ++mt)
                a[mt] = *(const short8*)(As + (m0 + mt * 16 + lm) * 72 + ks * 32 + kq * 8);
            if constexpr (B_NT) {
                #pragma unroll
                for (int nt = 0; nt < 2; ++nt)
                    b[nt] = *(const short8*)(Bs + (n0 + nt * 16 + lm) * 72 + ks * 32 + kq * 8);
            } else {
                #pragma unroll
                for (int nt = 0; nt < 2; ++nt)
                    #pragma unroll
                    for (int j = 0; j < 8; ++j)
                        b[nt][j] = (short)Bs[(ks * 32 + kq * 8 + j) * 68 + n0 + nt * 16 + lm];
            }
            #pragma unroll
            for (int mt = 0; mt < 2; ++mt)
                #pragma unroll
                for (int nt = 0; nt < 2; ++nt)
                    acc[mt][nt] = __builtin_amdgcn_mfma_f32_16x16x32_bf16(
                        a[mt], b[nt], acc[mt][nt], 0, 0, 0);
        }
    }
    // ---- epilogue ----
    #pragma unroll
    for (int mt = 0; mt < 2; ++mt)
        #pragma unroll
        for (int nt = 0; nt < 2; ++nt)
            #pragma unroll
            for (int r = 0; r < 4; ++r) {
                long row = bm + m0 + mt * 16 + kq * 4 + r;
                long col = bn + n0 + nt * 16 + lm;
                if constexpr (C_BF16)
                    ((ushort*)Cv)[(long)blockIdx.z * batchC + row * ldc + col] =
                        f2bf(acc[mt][nt][r]);
                else
                    ((float*)Cv)[(long)blockIdx.z * batchC + row * ldc + col] =
                        acc[mt][nt][r];
            }
}

// ---------------------------------------------------------------------------
// qb[:, :, 512:576] = bf16(rope(q_pe)) from fp32 qfull. fp64 angles.
// ---------------------------------------------------------------------------
__global__ __launch_bounds__(256) void pack_qrope(
    const float* __restrict__ qfull, const int* __restrict__ pos_q,
    ushort* __restrict__ qb)
{
    int id = blockIdx.x * 256 + threadIdx.x;     // T*H*32 = 131072
    int i = id & 31;
    int h = (id >> 5) & 15;
    int t = id >> 9;
    double inv = exp2(-(double)i * 0.41524101186092026);  // 10000^(-i/32)
    double f = (double)pos_q[t] * inv;
    double fr = f - floor(f * 0.15915494309189535) * 6.283185307179586;
    float sf, cf;
    sincosf((float)fr, &sf, &cf);
    float x1 = qfull[t * 3072 + h * 192 + 128 + i];
    float x2 = qfull[t * 3072 + h * 192 + 160 + i];
    ushort* q = qb + (long)(t * 16 + h) * 576;
    q[512 + i] = f2bf(x1 * cf - x2 * sf);
    q[544 + i] = f2bf(x2 * cf + x1 * sf);
}

// ---------------------------------------------------------------------------
// Precompute kvb[s][0:512]=bf16(kv_c[s]), kvb[s][512:576]=bf16(rope(k_pe[s],s)).
// (round-0 HW-verified form; 72 lanes/row)
// ---------------------------------------------------------------------------
__global__ __launch_bounds__(256) void prep_kvb(
    const float* __restrict__ kvc, const float* __restrict__ kpe,
    ushort* __restrict__ kvb)
{
    int id = blockIdx.x * 256 + threadIdx.x;   // 32768*72 = 2,359,296
    int s = id / 72;
    int c = id - s * 72;
    if (c < 64) {
        const float* src = kvc + (long)s * 512 + c * 8;
        float4 v0 = *(const float4*)src;
        float4 v1 = *(const float4*)(src + 4);
        ushort4 a, b;
        a.x = f2bf(v0.x); a.y = f2bf(v0.y); a.z = f2bf(v0.z); a.w = f2bf(v0.w);
        b.x = f2bf(v1.x); b.y = f2bf(v1.y); b.z = f2bf(v1.z); b.w = f2bf(v1.w);
        ushort* dst = kvb + (long)s * 576 + c * 8;
        *(ushort4*)dst = a;
        *(ushort4*)(dst + 4) = b;
    } else {
        int q = c - 64;                       // 0..7 -> rope dims q*8..q*8+7
        const float* kp = kpe + (long)s * 64;
        ushort* dst = kvb + (long)s * 576 + 512 + q * 8;
        #pragma unroll
        for (int e = 0; e < 8; ++e) {
            int d = q * 8 + e;
            int i = d & 31;
            double inv = exp2(-(double)i * 0.41524101186092026);
            double f = (double)s * inv;
            double fr = f - floor(f * 0.15915494309189535) * 6.283185307179586;
            float sf, cf;
            sincosf((float)fr, &sf, &cf);
            float x1 = kp[i], x2 = kp[32 + i];
            dst[e] = (d < 32) ? f2bf(x1 * cf - x2 * sf) : f2bf(x2 * cf + x1 * sf);
        }
    }
}

// ---------------------------------------------------------------------------
// Fused flash-MLA attention, split-K=2 (512 blocks, 1/CU).
//
// LDS key-tile layout, subtiled (HW-verified round 4):
//   off(s,d) = (d>>4)*2048 + (s>>2)*128 + (s&3)*32 + (d&15)*2
// ds_read_b64_tr_b16 semantics (HW-verified round 4): lane reads 8B at its
// own address; 16-lane group exchange: lane l elem j = block elem (l&15)+16j.
//
// Round-6 staging (replaces ds_write staging + the round-5 VGPR prefetch that
// SPILLED -> 597MB scratch writes):
//  - global_load_lds width 16: wave w stages keys 32(w&1)..+31, d-blocks
//    (w>>1)+2i. Lane l: key 32(w&1)+(l>>1), chunk db*16+(l&1)*8. LDS dst =
//    base(db,kh) + l*16 EXACTLY matches the subtiled layout (derived + spot-
//    checked: 128*(l>>3) + 32*((l>>1)&3) + 16*(l&1) == 16*l).
//  - double-buffered kb (2 x 73,728B; LDS total 150,016 -> 1 block/CU):
//    per tile: [syncthreads: prefetch landed] [issue next-tile gathers async]
//    [compute] -- gathers fly under the whole tile's compute.
//  - mid-tile softmax syncs use raw s_barrier + lgkmcnt(0) (NO vmcnt drain,
//    so in-flight gathers survive; __syncthreads would drain vmcnt(0)).
// PV counted-lgkmcnt pipeline byte-identical to round 5 (HW-passed).
// ---------------------------------------------------------------------------
#define KBD 2048    // d-block pitch in bytes (16 subtiles * 128B, dense)
#define KBSZ 73728  // one kb buffer (36 d-blocks)

__global__ __launch_bounds__(256, 1) void mla_fused_split(
    const ushort* __restrict__ qb, const ushort* __restrict__ kvb,
    const int* __restrict__ topk,
    ushort* __restrict__ Opart, float* __restrict__ ml)
{
    __shared__ __align__(16) char kb[2][KBSZ];    // 147,456 B double buffer
    __shared__ __align__(16) ushort P2[1024];     // P, key-subtiled (2 KiB)
    __shared__ float wred[2][4][16];              // [max|sum][wave][row]

    const int t = blockIdx.x;
    const int sp = blockIdx.y;          // split 0/1
    const int tid = threadIdx.x;
    const int w = tid >> 6;
    const int l = tid & 63;
    const int lm = l & 15;
    const int kq = l >> 4;

    // ---- preload Q A-fragments (18 k-steps of 32) ----
    short8 qa[18];
    {
        const ushort* qrow = qb + (long)(t * 16 + lm) * 576 + kq * 8;
        #pragma unroll
        for (int ks = 0; ks < 18; ++ks)
            qa[ks] = *(const short8*)(qrow + ks * 32);
    }

    const int* tkp = topk + (long)t * 2048 + sp * 1024;

    // staging roles
    const int kh   = w & 1;                    // key half (0: keys 0-31)
    const int db0  = w >> 1;                   // first d-block (step 2)
    const int skey = 32 * kh + (l >> 1);       // lane's key in tile
    const int gcol = db0 * 16 + (l & 1) * 8;   // lane's first element in row
    const unsigned stRel = (unsigned)(db0 * 2048 + kh * 1024);

    __attribute__((address_space(3))) char* kb3 =
        (__attribute__((address_space(3))) char*)&kb[0][0];

    const char* kbg = (const char*)&kb[0][0];
    const unsigned kbBase = (unsigned)(unsigned long long)(const void*)&kb[0][0];

    // QK B-fragment offset: key = w*16+lm, dim = ks*32 + kq*8
    const unsigned krowRel = (unsigned)((kq >> 1) * KBD + w * 512 + (lm >> 2) * 128
                     + (lm & 3) * 32 + (kq & 1) * 16);
    // PV tr-read offsets: lane lm owns the lm-th 8B chunk of each 4x16 tile
    const unsigned trRel = (unsigned)(w * 8 * KBD + kq * 256 + lm * 8);
    const unsigned ptrb = (unsigned)(unsigned long long)(const void*)P2
                        + (unsigned)(kq * 256 + lm * 8);

    f32x4 O[8];
    #pragma unroll
    for (int vt = 0; vt < 8; ++vt) O[vt] = (f32x4){0.f, 0.f, 0.f, 0.f};
    float m_r[4] = {-1e30f, -1e30f, -1e30f, -1e30f};
    float l_r[4] = {0.f, 0.f, 0.f, 0.f};

#define GSTAGE(IDX, BUFOFF)                                                   \
    {                                                                         \
        const ushort* gs = kvb + (long)(IDX) * 576 + gcol;                    \
        _Pragma("unroll")                                                     \
        for (int i = 0; i < 18; ++i)                                          \
            __builtin_amdgcn_global_load_lds(                                 \
                (const __attribute__((address_space(1))) void*)(const void*)(gs + i * 32), \
                (__attribute__((address_space(3))) void*)(kb3 + (BUFOFF) + stRel + i * 4096), \
                16, 0, 0);                                                    \
    }

    // ---- prologue: stage tile 0 into buf0; preload idx for tile 1 ----
    {
        int idx0 = tkp[skey];
        GSTAGE(idx0, 0u)
    }
    int nidx = tkp[64 + skey];

    for (int tt = 0; tt < 16; ++tt) {
        __syncthreads();   // implicit vmcnt(0): gathers(tt) landed; old buf free
        const unsigned bufC = (unsigned)((tt & 1) ? KBSZ : 0);
        // ---- issue next tile's gathers (fly under this tile's compute) ----
        if (tt + 1 < 16) {
            const unsigned bufN = (unsigned)KBSZ - bufC;
            GSTAGE(nidx, bufN)
            if (tt + 2 < 16) nidx = tkp[(tt + 2) * 64 + skey];
        }

        // ---- S = Q . K^T for this wave's 16 keys (2 chains) ----
        const char* krow = kbg + bufC + krowRel;
        f32x4 S0 = (f32x4){0.f, 0.f, 0.f, 0.f};
        f32x4 S1 = (f32x4){0.f, 0.f, 0.f, 0.f};
        #pragma unroll
        for (int ks = 0; ks < 18; ks += 2) {
            short8 b0 = *(const short8*)(krow + ks * (2 * KBD));
            S0 = __builtin_amdgcn_mfma_f32_16x16x32_bf16(qa[ks], b0, S0, 0, 0, 0);
            short8 b1 = *(const short8*)(krow + (ks + 1) * (2 * KBD));
            S1 = __builtin_amdgcn_mfma_f32_16x16x32_bf16(qa[ks + 1], b1, S1, 0, 0, 0);
        }
        float s4[4], mx[4], p[4];
        #pragma unroll
        for (int r = 0; r < 4; ++r) { s4[r] = (S0[r] + S1[r]) * SCALE_; mx[r] = s4[r]; }
        #pragma unroll
        for (int off = 1; off < 16; off <<= 1)
            #pragma unroll
            for (int r = 0; r < 4; ++r)
                mx[r] = fmaxf(mx[r], __shfl_xor(mx[r], off, 64));
        if (lm == 0)
            #pragma unroll
            for (int r = 0; r < 4; ++r) wred[0][w][4 * kq + r] = mx[r];
        // raw barrier: lgkm drained, vmcnt (gathers) NOT drained
        asm volatile("s_waitcnt lgkmcnt(0)" ::: "memory");
        __builtin_amdgcn_s_barrier();
        asm volatile("" ::: "memory");

        float al[4], rs[4];
        #pragma unroll
        for (int r = 0; r < 4; ++r) {
            float tm = fmaxf(fmaxf(wred[0][0][4 * kq + r], wred[0][1][4 * kq + r]),
                             fmaxf(wred[0][2][4 * kq + r], wred[0][3][4 * kq + r]));
            float mn = fmaxf(m_r[r], tm);
            al[r] = exp2f((m_r[r] - mn) * LOG2E_);
            p[r] = exp2f((s4[r] - mn) * LOG2E_);
            m_r[r] = mn;
            rs[r] = p[r];
        }
        #pragma unroll
        for (int off = 1; off < 16; off <<= 1)
            #pragma unroll
            for (int r = 0; r < 4; ++r)
                rs[r] += __shfl_xor(rs[r], off, 64);
        if (lm == 0)
            #pragma unroll
            for (int r = 0; r < 4; ++r) wred[1][w][4 * kq + r] = rs[r];
        // P write: key = w*16+lm, heads 4kq..4kq+3 consecutive -> one b64 store
        {
            ushort4 pu;
            pu.x = f2bf(p[0]); pu.y = f2bf(p[1]);
            pu.z = f2bf(p[2]); pu.w = f2bf(p[3]);
            *(ushort4*)(P2 + (w * 4 + (lm >> 2)) * 64 + (lm & 3) * 16 + 4 * kq) = pu;
        }
        #pragma unroll
        for (int vt = 0; vt < 8; ++vt)
            #pragma unroll
            for (int r = 0; r < 4; ++r)
                O[vt][r] *= al[r];
        // raw barrier: P2 + wred[1] visible; gathers still in flight
        asm volatile("s_waitcnt lgkmcnt(0)" ::: "memory");
        __builtin_amdgcn_s_barrier();
        asm volatile("" ::: "memory");

        #pragma unroll
        for (int r = 0; r < 4; ++r) {
            float ts = wred[1][0][4 * kq + r] + wred[1][1][4 * kq + r] +
                       wred[1][2][4 * kq + r] + wred[1][3][4 * kq + r];
            l_r[r] = l_r[r] * al[r] + ts;
        }

        // ---- O += P . V : software-pipelined tr reads (counted lgkmcnt) ----
        const unsigned trb = kbBase + bufC + trRel;
        __builtin_amdgcn_sched_barrier(0);
        short4v pr[4];
        asm volatile("ds_read_b64_tr_b16 %0, %1 offset:0"    : "=v"(pr[0]) : "v"(ptrb));
        asm volatile("ds_read_b64_tr_b16 %0, %1 offset:128"  : "=v"(pr[1]) : "v"(ptrb));
        asm volatile("ds_read_b64_tr_b16 %0, %1 offset:1024" : "=v"(pr[2]) : "v"(ptrb));
        asm volatile("ds_read_b64_tr_b16 %0, %1 offset:1152" : "=v"(pr[3]) : "v"(ptrb));
        short4v rg[4][4];
#define ISSUE_V(vt, slot) \
        asm volatile("ds_read_b64_tr_b16 %0, %1 offset:%2" : "=v"(rg[slot][0]) : "v"(trb), "i"((vt) * KBD));        \
        asm volatile("ds_read_b64_tr_b16 %0, %1 offset:%2" : "=v"(rg[slot][1]) : "v"(trb), "i"((vt) * KBD + 128));  \
        asm volatile("ds_read_b64_tr_b16 %0, %1 offset:%2" : "=v"(rg[slot][2]) : "v"(trb), "i"((vt) * KBD + 1024)); \
        asm volatile("ds_read_b64_tr_b16 %0, %1 offset:%2" : "=v"(rg[slot][3]) : "v"(trb), "i"((vt) * KBD + 1152));
        ISSUE_V(0, 0)
        ISSUE_V(1, 1)
        asm volatile("s_waitcnt lgkmcnt(8)" ::: "memory");   // pr ready
        __builtin_amdgcn_sched_barrier(0);
        short8 pa0 = __builtin_shufflevector(pr[0], pr[1], 0, 1, 2, 3, 4, 5, 6, 7);
        short8 pa1 = __builtin_shufflevector(pr[2], pr[3], 0, 1, 2, 3, 4, 5, 6, 7);
        #pragma unroll
        for (int vt = 0; vt < 8; ++vt) {
            if (vt < 6) { ISSUE_V(vt + 2, (vt + 2) & 3) }
            if (vt < 6)
                asm volatile("s_waitcnt lgkmcnt(8)" ::: "memory");  // chunk vt ready
            else if (vt == 6)
                asm volatile("s_waitcnt lgkmcnt(4)" ::: "memory");
            else
                asm volatile("s_waitcnt lgkmcnt(0)" ::: "memory");
            __builtin_amdgcn_sched_barrier(0);
            short8 bv0 = __builtin_shufflevector(rg[vt & 3][0], rg[vt & 3][1],
                                                 0, 1, 2, 3, 4, 5, 6, 7);
            O[vt] = __builtin_amdgcn_mfma_f32_16x16x32_bf16(pa0, bv0, O[vt], 0, 0, 0);
            short8 bv1 = __builtin_shufflevector(rg[vt & 3][2], rg[vt & 3][3],
                                                 0, 1, 2, 3, 4, 5, 6, 7);
            O[vt] = __builtin_amdgcn_mfma_f32_16x16x32_bf16(pa1, bv1, O[vt], 0, 0, 0);
        }
#undef ISSUE_V
    }

    // ---- epilogue: store unnormalized partial O (bf16) + (m,l) ----
    const long rbase = ((long)sp * 256 + t) * 16;
    #pragma unroll
    for (int vt = 0; vt < 8; ++vt)
        #pragma unroll
        for (int r = 0; r < 4; ++r)
            Opart[(rbase + 4 * kq + r) * 512 + w * 128 + vt * 16 + lm] = f2bf(O[vt][r]);
    if (w == 0 && lm == 0) {
        #pragma unroll
        for (int r = 0; r < 4; ++r) {
            ml[(rbase + 4 * kq + r) * 2 + 0] = m_r[r];
            ml[(rbase + 4 * kq + r) * 2 + 1] = l_r[r];
        }
    }
#undef GSTAGE
}

// ---------------------------------------------------------------------------
// Merge the 2 split-K partials -> olat bf16.
// ---------------------------------------------------------------------------
__global__ __launch_bounds__(256) void combine_kernel(
    const ushort* __restrict__ Opart, const float* __restrict__ ml,
    ushort* __restrict__ olat)
{
    const int t = blockIdx.x;
    const int h = threadIdx.x >> 4;
    const int v0 = (threadIdx.x & 15) * 32;
    const long r0 = (long)t * 16 + h;
    const long r1 = (long)(256 + t) * 16 + h;
    float m0 = ml[r0 * 2], l0 = ml[r0 * 2 + 1];
    float m1 = ml[r1 * 2], l1 = ml[r1 * 2 + 1];
    float M = fmaxf(m0, m1);
    float w0 = exp2f((m0 - M) * LOG2E_);
    float w1 = exp2f((m1 - M) * LOG2E_);
    float inv = 1.0f / (w0 * l0 + w1 * l1);
    const ushort* p0 = Opart + r0 * 512 + v0;
    const ushort* p1 = Opart + r1 * 512 + v0;
    ushort* po = olat + r0 * 512 + v0;
    #pragma unroll
    for (int i = 0; i < 32; i += 4) {
        ushort4 a = *(const ushort4*)(p0 + i);
        ushort4 b = *(const ushort4*)(p1 + i);
        ushort4 o;
        o.x = f2bf((w0 * bf2f(a.x) + w1 * bf2f(b.x)) * inv);
        o.y = f2bf((w0 * bf2f(a.y) + w1 * bf2f(b.y)) * inv);
        o.z = f2bf((w0 * bf2f(a.z) + w1 * bf2f(b.z)) * inv);
        o.w = f2bf((w0 * bf2f(a.w) + w1 * bf2f(b.w)) * inv);
        *(ushort4*)(po + i) = o;
    }
}

// ---------------------------------------------------------------------------
// Launch. ws footprint exactly 54,001,664 B (proven safe in R5).
// ---------------------------------------------------------------------------
extern "C" void kernel_launch(void* const* d_in, const int* in_sizes, int n_in,
                              void* d_out, int out_size, void* d_ws, size_t ws_size,
                              hipStream_t stream)
{
    const float* x    = (const float*)d_in[0];
    const float* Wq   = (const float*)d_in[1];
    const float* W_UK = (const float*)d_in[2];
    const float* W_UV = (const float*)d_in[3];
    const float* Wo   = (const float*)d_in[4];
    const float* kv_c = (const float*)d_in[5];
    const float* k_pe = (const float*)d_in[6];
    const int* topk   = (const int*)d_in[7];
    const int* pos_q  = (const int*)d_in[8];
    float* out        = (float*)d_out;

    char* wsb = (char*)d_ws;
    ushort* qb    = (ushort*)wsb;
    float*  qfull = (float*)(wsb + 4718592);
    ushort* Opart = (ushort*)(wsb + 4718592);          // overlay of qfull
    ushort* ov_b  = (ushort*)(wsb + 13107200);
    float*  ml    = (float*)(wsb + 14155776);
    ushort* olat  = qb;                                // overlay (qb dead)
    ushort* kvb   = (ushort*)(wsb + 16252928);
    if (ws_size < (size_t)54001664) return;            // fail loud, don't fault

    // 0) prep bf16 kv table
    prep_kvb<<<9216, 256, 0, stream>>>(kv_c, k_pe, kvb);

    // 1) qfull = x @ Wq   (256 x 3072 x 2048), fp32 out
    gemm_mfma<false, false, false><<<dim3(48, 4), 256, 0, stream>>>(
        x, Wq, qfull, 256, 3072, 2048, 2048, 3072, 3072, 0, 0, 0);

    // 2) qb[:, :, 0:512] = qnope @ W_UK[h]  (256 x 512 x 128, batched over h)
    gemm_mfma<false, false, true><<<dim3(8, 4, 16), 256, 0, stream>>>(
        qfull, W_UK, qb, 256, 512, 128, 3072, 512, 9216, 192, 65536, 576);

    // 3) qb[:, :, 512:576] = bf16(rope(q_pe))
    pack_qrope<<<512, 256, 0, stream>>>(qfull, pos_q, qb);

    // 4) fused attention, split-K=2 -> partials
    mla_fused_split<<<dim3(256, 2), 256, 0, stream>>>(qb, kvb, topk, Opart, ml);

    // 5) combine partials -> olat (bf16, overlays qb)
    combine_kernel<<<256, 256, 0, stream>>>(Opart, ml, olat);

    // 6) ov_b[t, h*128+v] = olat[t,h,:] . W_UV[h,v,:]  (NT, A bf16, C bf16)
    gemm_mfma<true, true, true><<<dim3(2, 4, 16), 256, 0, stream>>>(
        olat, W_UV, ov_b, 256, 128, 512, 8192, 512, 2048, 512, 65536, 128);

    // 7) out = ov_b @ Wo   (256 x 2048 x 2048), fp32 out
    gemm_mfma<true, false, false><<<dim3(32, 4), 256, 0, stream>>>(
        ov_b, Wo, out, 256, 2048, 2048, 2048, 2048, 2048, 0, 0, 0);
}

// Round 7
// 322.953 us; speedup vs baseline: 1.8143x; 1.3959x over previous
//
#include <hip/hip_runtime.h>
#include <hip/hip_bf16.h>

// Problem constants
#define H_    16
#define NOPE_ 128
#define ROPE_ 64
#define VDIM_ 128
#define LORA_ 512
#define DM_   2048
#define T_    256
#define S_    32768
#define K_    2048

static constexpr float SCALE_ = 0.072168783648703220563643597562744f; // 1/sqrt(192)
static constexpr float LOG2E_ = 1.4426950408889634f;

typedef __attribute__((ext_vector_type(8))) short short8;   // 8 bf16 in 4 VGPRs
typedef __attribute__((ext_vector_type(4))) short short4v;  // 4 bf16 in 2 VGPRs
typedef __attribute__((ext_vector_type(4))) float f32x4;    // MFMA accumulator

__device__ __forceinline__ ushort f2bf(float f) {
    unsigned u = __float_as_uint(f);
    unsigned r = (u + 0x7FFFu + ((u >> 16) & 1u)) >> 16;    // RNE
    return (ushort)r;
}
__device__ __forceinline__ float bf2f(ushort u) {
    return __uint_as_float((unsigned)u << 16);
}

// ---------------------------------------------------------------------------
// bf16 MFMA GEMM: C[M,N] = A[M,K] @ B[K,N] (B_NT: B is [N][K] n-major).
// BM=BN=64, BK=64, 256 thr (4 waves, each a 32x32 quadrant, 2x2 MFMA tiles).
// Round-7: register double-buffer prefetch — next k-tile's global loads are
// issued right after the current tile's LDS stores, so they fly under the
// MFMA compute instead of serializing each of the K/64 iterations on cold
// load latency (GEMM1 has only 192 blocks = 0.75 waves/SIMD: zero TLP to
// hide it otherwise). ~24-32 extra VGPRs; 4 waves/block on 4 SIMDs -> no
// occupancy cliff risk.
// ---------------------------------------------------------------------------
template<bool A_BF16, bool B_NT, bool C_BF16>
__global__ __launch_bounds__(256) void gemm_mfma(
    const void* __restrict__ Av, const float* __restrict__ B, void* __restrict__ Cv,
    int M, int N, int Kd, int lda, int ldb, int ldc,
    long batchA, long batchB, long batchC)
{
    __shared__ ushort As[64 * 72];
    __shared__ ushort Bs[64 * 72];

    const int tid = threadIdx.x;
    const int w  = tid >> 6;
    const int l  = tid & 63;
    const int lm = l & 15;
    const int kq = l >> 4;
    const int bm = blockIdx.y * 64;
    const int bn = blockIdx.x * 64;
    const int m0 = (w >> 1) * 32;
    const int n0 = (w & 1) * 32;

    const float*  Af = A_BF16 ? nullptr : ((const float*)Av)  + (long)blockIdx.z * batchA;
    const ushort* Ah = A_BF16 ? ((const ushort*)Av) + (long)blockIdx.z * batchA : nullptr;
    B += (long)blockIdx.z * batchB;

    f32x4 acc[2][2];
    #pragma unroll
    for (int i = 0; i < 2; ++i)
        #pragma unroll
        for (int j = 0; j < 2; ++j) acc[i][j] = (f32x4){0.f, 0.f, 0.f, 0.f};

    // staging address components
    const int am  = tid >> 2, ako = (tid & 3) * 16;          // A_BF16
    const int amr = tid >> 4, akk = (tid & 15) * 4;          // A fp32
    const int bnr = tid >> 4, bkk = (tid & 15) * 4;          // B_NT
    const int bk  = tid >> 2, bnq = (tid & 3) * 16;          // B_NN

    // register prefetch buffers
    uint4  gA[2];
    float4 gAf[4];
    float4 gB[4];

    auto loadA = [&](int k0) {
        if constexpr (A_BF16) {
            const ushort* src = Ah + (long)(bm + am) * lda + k0 + ako;
            gA[0] = *(const uint4*)(src);
            gA[1] = *(const uint4*)(src + 8);
        } else {
            #pragma unroll
            for (int p = 0; p < 4; ++p)
                gAf[p] = *(const float4*)(Af + (long)(bm + amr + p * 16) * lda + k0 + akk);
        }
    };
    auto loadB = [&](int k0) {
        if constexpr (B_NT) {
            #pragma unroll
            for (int p = 0; p < 4; ++p)
                gB[p] = *(const float4*)(B + (long)(bn + bnr + p * 16) * ldb + k0 + bkk);
        } else {
            #pragma unroll
            for (int p = 0; p < 4; ++p)
                gB[p] = *(const float4*)(B + (long)(k0 + bk) * ldb + bn + bnq + p * 4);
        }
    };

    loadA(0); loadB(0);

    for (int k0 = 0; k0 < Kd; k0 += 64) {
        __syncthreads();
        // ---- store prefetched regs -> LDS (with bf16 conversion) ----
        if constexpr (A_BF16) {
            *(uint4*)(As + am * 72 + ako)     = gA[0];
            *(uint4*)(As + am * 72 + ako + 8) = gA[1];
        } else {
            #pragma unroll
            for (int p = 0; p < 4; ++p) {
                ushort4 u;
                u.x = f2bf(gAf[p].x); u.y = f2bf(gAf[p].y);
                u.z = f2bf(gAf[p].z); u.w = f2bf(gAf[p].w);
                *(ushort4*)(As + (amr + p * 16) * 72 + akk) = u;
            }
        }
        if constexpr (B_NT) {
            #pragma unroll
            for (int p = 0; p < 4; ++p) {
                ushort4 u;
                u.x = f2bf(gB[p].x); u.y = f2bf(gB[p].y);
                u.z = f2bf(gB[p].z); u.w = f2bf(gB[p].w);
                *(ushort4*)(Bs + (bnr + p * 16) * 72 + bkk) = u;
            }
        } else {
            #pragma unroll
            for (int p = 0; p < 4; ++p) {
                ushort4 u;
                u.x = f2bf(gB[p].x); u.y = f2bf(gB[p].y);
                u.z = f2bf(gB[p].z); u.w = f2bf(gB[p].w);
                *(ushort4*)(Bs + bk * 68 + bnq + p * 4) = u;
            }
        }
        // ---- issue next tile's loads (fly under compute) ----
        if (k0 + 64 < Kd) { loadA(k0 + 64); loadB(k0 + 64); }
        __syncthreads();
        // ---- compute: 2 k-steps of 32 ----
        #pragma unroll
        for (int ks = 0; ks < 2; ++ks) {
            short8 a[2], b[2];
            #pragma unroll
            for (int mt = 0; mt < 2; ++mt)
                a[mt] = *(const short8*)(As + (m0 + mt * 16 + lm) * 72 + ks * 32 + kq * 8);
            if constexpr (B_NT) {
                #pragma unroll
                for (int nt = 0; nt < 2; ++nt)
                    b[nt] = *(const short8*)(Bs + (n0 + nt * 16 + lm) * 72 + ks * 32 + kq * 8);
            } else {
                #pragma unroll
                for (int nt = 0; nt < 2; ++nt)
                    #pragma unroll
                    for (int j = 0; j < 8; ++j)
                        b[nt][j] = (short)Bs[(ks * 32 + kq * 8 + j) * 68 + n0 + nt * 16 + lm];
            }
            #pragma unroll
            for (int mt = 0; mt < 2; ++mt)
                #pragma unroll
                for (int nt = 0; nt < 2; ++nt)
                    acc[mt][nt] = __builtin_amdgcn_mfma_f32_16x16x32_bf16(
                        a[mt], b[nt], acc[mt][nt], 0, 0, 0);
        }
    }
    // ---- epilogue ----
    #pragma unroll
    for (int mt = 0; mt < 2; ++mt)
        #pragma unroll
        for (int nt = 0; nt < 2; ++nt)
            #pragma unroll
            for (int r = 0; r < 4; ++r) {
                long row = bm + m0 + mt * 16 + kq * 4 + r;
                long col = bn + n0 + nt * 16 + lm;
                if constexpr (C_BF16)
                    ((ushort*)Cv)[(long)blockIdx.z * batchC + row * ldc + col] =
                        f2bf(acc[mt][nt][r]);
                else
                    ((float*)Cv)[(long)blockIdx.z * batchC + row * ldc + col] =
                        acc[mt][nt][r];
            }
}

// ---------------------------------------------------------------------------
// qb[:, :, 512:576] = bf16(rope(q_pe)) from fp32 qfull. fp64 angles.
// ---------------------------------------------------------------------------
__global__ __launch_bounds__(256) void pack_qrope(
    const float* __restrict__ qfull, const int* __restrict__ pos_q,
    ushort* __restrict__ qb)
{
    int id = blockIdx.x * 256 + threadIdx.x;     // T*H*32 = 131072
    int i = id & 31;
    int h = (id >> 5) & 15;
    int t = id >> 9;
    double inv = exp2(-(double)i * 0.41524101186092026);  // 10000^(-i/32)
    double f = (double)pos_q[t] * inv;
    double fr = f - floor(f * 0.15915494309189535) * 6.283185307179586;
    float sf, cf;
    sincosf((float)fr, &sf, &cf);
    float x1 = qfull[t * 3072 + h * 192 + 128 + i];
    float x2 = qfull[t * 3072 + h * 192 + 160 + i];
    ushort* q = qb + (long)(t * 16 + h) * 576;
    q[512 + i] = f2bf(x1 * cf - x2 * sf);
    q[544 + i] = f2bf(x2 * cf + x1 * sf);
}

// ---------------------------------------------------------------------------
// Precompute kvb[s][0:512]=bf16(kv_c[s]), kvb[s][512:576]=bf16(rope(k_pe[s],s)).
// 96 lanes/row: 64 convert lanes + 32 rope lanes (one angle each; d and d+32
// share i/cos/sin). Element math identical to the 72-lane HW-verified form;
// only the lane->work mapping changes (divergent fp64 tail 8x shorter).
// ---------------------------------------------------------------------------
__global__ __launch_bounds__(256) void prep_kvb(
    const float* __restrict__ kvc, const float* __restrict__ kpe,
    ushort* __restrict__ kvb)
{
    int id = blockIdx.x * 256 + threadIdx.x;   // 32768*96 = 3,145,728
    int s = id / 96;
    int c = id - s * 96;
    if (c < 64) {
        const float* src = kvc + (long)s * 512 + c * 8;
        float4 v0 = *(const float4*)src;
        float4 v1 = *(const float4*)(src + 4);
        ushort4 a, b;
        a.x = f2bf(v0.x); a.y = f2bf(v0.y); a.z = f2bf(v0.z); a.w = f2bf(v0.w);
        b.x = f2bf(v1.x); b.y = f2bf(v1.y); b.z = f2bf(v1.z); b.w = f2bf(v1.w);
        ushort* dst = kvb + (long)s * 576 + c * 8;
        *(ushort4*)dst = a;
        *(ushort4*)(dst + 4) = b;
    } else {
        int i = c - 64;                       // 0..31
        double inv = exp2(-(double)i * 0.41524101186092026);
        double f = (double)s * inv;
        double fr = f - floor(f * 0.15915494309189535) * 6.283185307179586;
        float sf, cf;
        sincosf((float)fr, &sf, &cf);
        const float* kp = kpe + (long)s * 64;
        float x1 = kp[i], x2 = kp[32 + i];
        ushort* dst = kvb + (long)s * 576 + 512;
        dst[i]      = f2bf(x1 * cf - x2 * sf);
        dst[32 + i] = f2bf(x2 * cf + x1 * sf);
    }
}

// ---------------------------------------------------------------------------
// Fused flash-MLA attention, split-K=2 (512 blocks).
//
// LDS key-tile layout, subtiled (HW-verified round 4):
//   off(s,d) = (d>>4)*2048 + (s>>2)*128 + (s&3)*32 + (d&15)*2
// ds_read_b64_tr_b16 semantics (HW-verified round 4): lane reads 8B at its
// own address; 16-lane group exchange: lane l elem j = block elem (l&15)+16j.
// global_load_lds staging mapping (HW-verified round 6): wave w stages keys
// 32(w&1)+(l>>1), chunks (w>>1)*16+(l&1)*8 (+32/iter); dst = base + l*16.
//
// Round-7 occupancy fix: rounds 4/6 sat at ~11% occupancy. Two cliffs found:
//  - LDS: round-6 dbuf = 150KB -> 1 block/CU. Fix: single buffer (76,288B).
//  - VGPR: >128 gates 8 waves/CU (round 0: VGPR=120 -> 19.4%; round 4:
//    VGPR=132, same LDS -> 11%). Fix: __launch_bounds__(256,4) caps at 128;
//    pressure shaved via rg[2][4] PV ring (was [4][4]) + dbuf vars deleted.
// Gather is issue -> vmcnt(0) -> barrier per tile (intra-block exposed);
// with 2 blocks/CU the co-resident block's compute hides it (m114), same
// mechanism round 0 relied on — minus its ds_write staging + scalar PV cost.
// WRITE_SIZE is the spill tripwire (round-5 lesson: 597MB = scratch).
// ---------------------------------------------------------------------------
#define KBD 2048    // d-block pitch in bytes (16 subtiles * 128B, dense)
#define KBSZ 73728  // kb buffer (36 d-blocks)

__global__ __launch_bounds__(256, 4) void mla_fused_split(
    const ushort* __restrict__ qb, const ushort* __restrict__ kvb,
    const int* __restrict__ topk,
    ushort* __restrict__ Opart, float* __restrict__ ml)
{
    __shared__ __align__(16) char kb[KBSZ];       // 73,728 B single buffer
    __shared__ __align__(16) ushort P2[1024];     // P, key-subtiled (2 KiB)
    __shared__ float wred[2][4][16];              // [max|sum][wave][row]

    const int t = blockIdx.x;
    const int sp = blockIdx.y;          // split 0/1
    const int tid = threadIdx.x;
    const int w = tid >> 6;
    const int l = tid & 63;
    const int lm = l & 15;
    const int kq = l >> 4;

    // ---- preload Q A-fragments (18 k-steps of 32) ----
    short8 qa[18];
    {
        const ushort* qrow = qb + (long)(t * 16 + lm) * 576 + kq * 8;
        #pragma unroll
        for (int ks = 0; ks < 18; ++ks)
            qa[ks] = *(const short8*)(qrow + ks * 32);
    }

    const int* tkp = topk + (long)t * 2048 + sp * 1024;

    // staging roles (HW-verified round 6)
    const int kh   = w & 1;                    // key half (0: keys 0-31)
    const int db0  = w >> 1;                   // first d-block (step 2)
    const int skey = 32 * kh + (l >> 1);       // lane's key in tile
    const int gcol = db0 * 16 + (l & 1) * 8;   // lane's first element in row
    const unsigned stRel = (unsigned)(db0 * 2048 + kh * 1024);

    __attribute__((address_space(3))) char* kb3 =
        (__attribute__((address_space(3))) char*)&kb[0];
    const char* kbg = (const char*)&kb[0];
    const unsigned kbBase = (unsigned)(unsigned long long)(const void*)&kb[0];

    // QK B-fragment offset: key = w*16+lm, dim = ks*32 + kq*8
    const unsigned krowRel = (unsigned)((kq >> 1) * KBD + w * 512 + (lm >> 2) * 128
                     + (lm & 3) * 32 + (kq & 1) * 16);
    // PV tr-read offsets: lane lm owns the lm-th 8B chunk of each 4x16 tile
    const unsigned trb = kbBase + (unsigned)(w * 8 * KBD + kq * 256 + lm * 8);
    const unsigned ptrb = (unsigned)(unsigned long long)(const void*)P2
                        + (unsigned)(kq * 256 + lm * 8);

    f32x4 O[8];
    #pragma unroll
    for (int vt = 0; vt < 8; ++vt) O[vt] = (f32x4){0.f, 0.f, 0.f, 0.f};
    float m_r[4] = {-1e30f, -1e30f, -1e30f, -1e30f};
    float l_r[4] = {0.f, 0.f, 0.f, 0.f};

#define GSTAGE(IDX)                                                           \
    {                                                                         \
        const ushort* gs = kvb + (long)(IDX) * 576 + gcol;                    \
        _Pragma("unroll")                                                     \
        for (int i = 0; i < 18; ++i)                                          \
            __builtin_amdgcn_global_load_lds(                                 \
                (const __attribute__((address_space(1))) void*)(const void*)(gs + i * 32), \
                (__attribute__((address_space(3))) void*)(kb3 + stRel + i * 4096), \
                16, 0, 0);                                                    \
    }

    for (int tt = 0; tt < 16; ++tt) {
        int idx = tkp[tt * 64 + skey];
        __syncthreads();   // prev tile fully consumed (PV reads drained)
        GSTAGE(idx)
        asm volatile("s_waitcnt vmcnt(0)" ::: "memory");
        __builtin_amdgcn_s_barrier();
        asm volatile("" ::: "memory");   // kb ready

        // ---- S = Q . K^T for this wave's 16 keys (2 chains) ----
        const char* krow = kbg + krowRel;
        f32x4 S0 = (f32x4){0.f, 0.f, 0.f, 0.f};
        f32x4 S1 = (f32x4){0.f, 0.f, 0.f, 0.f};
        #pragma unroll
        for (int ks = 0; ks < 18; ks += 2) {
            short8 b0 = *(const short8*)(krow + ks * (2 * KBD));
            S0 = __builtin_amdgcn_mfma_f32_16x16x32_bf16(qa[ks], b0, S0, 0, 0, 0);
            short8 b1 = *(const short8*)(krow + (ks + 1) * (2 * KBD));
            S1 = __builtin_amdgcn_mfma_f32_16x16x32_bf16(qa[ks + 1], b1, S1, 0, 0, 0);
        }
        float s4[4], mx[4], p[4];
        #pragma unroll
        for (int r = 0; r < 4; ++r) { s4[r] = (S0[r] + S1[r]) * SCALE_; mx[r] = s4[r]; }
        #pragma unroll
        for (int off = 1; off < 16; off <<= 1)
            #pragma unroll
            for (int r = 0; r < 4; ++r)
                mx[r] = fmaxf(mx[r], __shfl_xor(mx[r], off, 64));
        if (lm == 0)
            #pragma unroll
            for (int r = 0; r < 4; ++r) wred[0][w][4 * kq + r] = mx[r];
        asm volatile("s_waitcnt lgkmcnt(0)" ::: "memory");
        __builtin_amdgcn_s_barrier();
        asm volatile("" ::: "memory");

        float al[4], rs[4];
        #pragma unroll
        for (int r = 0; r < 4; ++r) {
            float tm = fmaxf(fmaxf(wred[0][0][4 * kq + r], wred[0][1][4 * kq + r]),
                             fmaxf(wred[0][2][4 * kq + r], wred[0][3][4 * kq + r]));
            float mn = fmaxf(m_r[r], tm);
            al[r] = exp2f((m_r[r] - mn) * LOG2E_);
            p[r] = exp2f((s4[r] - mn) * LOG2E_);
            m_r[r] = mn;
            rs[r] = p[r];
        }
        #pragma unroll
        for (int off = 1; off < 16; off <<= 1)
            #pragma unroll
            for (int r = 0; r < 4; ++r)
                rs[r] += __shfl_xor(rs[r], off, 64);
        if (lm == 0)
            #pragma unroll
            for (int r = 0; r < 4; ++r) wred[1][w][4 * kq + r] = rs[r];
        // P write: key = w*16+lm, heads 4kq..4kq+3 consecutive -> one b64 store
        {
            ushort4 pu;
            pu.x = f2bf(p[0]); pu.y = f2bf(p[1]);
            pu.z = f2bf(p[2]); pu.w = f2bf(p[3]);
            *(ushort4*)(P2 + (w * 4 + (lm >> 2)) * 64 + (lm & 3) * 16 + 4 * kq) = pu;
        }
        #pragma unroll
        for (int vt = 0; vt < 8; ++vt)
            #pragma unroll
            for (int r = 0; r < 4; ++r)
                O[vt][r] *= al[r];
        asm volatile("s_waitcnt lgkmcnt(0)" ::: "memory");
        __builtin_amdgcn_s_barrier();
        asm volatile("" ::: "memory");   // P2 + wred[1] visible

        #pragma unroll
        for (int r = 0; r < 4; ++r) {
            float ts = wred[1][0][4 * kq + r] + wred[1][1][4 * kq + r] +
                       wred[1][2][4 * kq + r] + wred[1][3][4 * kq + r];
            l_r[r] = l_r[r] * al[r] + ts;
        }

        // ---- O += P . V : 2-slot pipelined tr reads (counted lgkmcnt) ----
        __builtin_amdgcn_sched_barrier(0);
        short4v pr[4];
        asm volatile("ds_read_b64_tr_b16 %0, %1 offset:0"    : "=v"(pr[0]) : "v"(ptrb));
        asm volatile("ds_read_b64_tr_b16 %0, %1 offset:128"  : "=v"(pr[1]) : "v"(ptrb));
        asm volatile("ds_read_b64_tr_b16 %0, %1 offset:1024" : "=v"(pr[2]) : "v"(ptrb));
        asm volatile("ds_read_b64_tr_b16 %0, %1 offset:1152" : "=v"(pr[3]) : "v"(ptrb));
        short4v rg[2][4];
#define ISSUE_V(vt, slot) \
        asm volatile("ds_read_b64_tr_b16 %0, %1 offset:%2" : "=v"(rg[slot][0]) : "v"(trb), "i"((vt) * KBD));        \
        asm volatile("ds_read_b64_tr_b16 %0, %1 offset:%2" : "=v"(rg[slot][1]) : "v"(trb), "i"((vt) * KBD + 128));  \
        asm volatile("ds_read_b64_tr_b16 %0, %1 offset:%2" : "=v"(rg[slot][2]) : "v"(trb), "i"((vt) * KBD + 1024)); \
        asm volatile("ds_read_b64_tr_b16 %0, %1 offset:%2" : "=v"(rg[slot][3]) : "v"(trb), "i"((vt) * KBD + 1152));
        ISSUE_V(0, 0)
        ISSUE_V(1, 1)
        asm volatile("s_waitcnt lgkmcnt(8)" ::: "memory");   // pr ready
        __builtin_amdgcn_sched_barrier(0);
        short8 pa0 = __builtin_shufflevector(pr[0], pr[1], 0, 1, 2, 3, 4, 5, 6, 7);
        short8 pa1 = __builtin_shufflevector(pr[2], pr[3], 0, 1, 2, 3, 4, 5, 6, 7);
        #pragma unroll
        for (int vt = 0; vt < 8; ++vt) {
            if (vt < 7)
                asm volatile("s_waitcnt lgkmcnt(4)" ::: "memory");  // chunk vt ready
            else
                asm volatile("s_waitcnt lgkmcnt(0)" ::: "memory");
            __builtin_amdgcn_sched_barrier(0);
            short8 bv0 = __builtin_shufflevector(rg[vt & 1][0], rg[vt & 1][1],
                                                 0, 1, 2, 3, 4, 5, 6, 7);
            O[vt] = __builtin_amdgcn_mfma_f32_16x16x32_bf16(pa0, bv0, O[vt], 0, 0, 0);
            short8 bv1 = __builtin_shufflevector(rg[vt & 1][2], rg[vt & 1][3],
                                                 0, 1, 2, 3, 4, 5, 6, 7);
            O[vt] = __builtin_amdgcn_mfma_f32_16x16x32_bf16(pa1, bv1, O[vt], 0, 0, 0);
            if (vt < 6) { ISSUE_V(vt + 2, vt & 1) }   // slot now free
        }
#undef ISSUE_V
    }

    // ---- epilogue: store unnormalized partial O (bf16) + (m,l) ----
    const long rbase = ((long)sp * 256 + t) * 16;
    #pragma unroll
    for (int vt = 0; vt < 8; ++vt)
        #pragma unroll
        for (int r = 0; r < 4; ++r)
            Opart[(rbase + 4 * kq + r) * 512 + w * 128 + vt * 16 + lm] = f2bf(O[vt][r]);
    if (w == 0 && lm == 0) {
        #pragma unroll
        for (int r = 0; r < 4; ++r) {
            ml[(rbase + 4 * kq + r) * 2 + 0] = m_r[r];
            ml[(rbase + 4 * kq + r) * 2 + 1] = l_r[r];
        }
    }
#undef GSTAGE
}

// ---------------------------------------------------------------------------
// Merge the 2 split-K partials -> olat bf16.
// ---------------------------------------------------------------------------
__global__ __launch_bounds__(256) void combine_kernel(
    const ushort* __restrict__ Opart, const float* __restrict__ ml,
    ushort* __restrict__ olat)
{
    const int t = blockIdx.x;
    const int h = threadIdx.x >> 4;
    const int v0 = (threadIdx.x & 15) * 32;
    const long r0 = (long)t * 16 + h;
    const long r1 = (long)(256 + t) * 16 + h;
    float m0 = ml[r0 * 2], l0 = ml[r0 * 2 + 1];
    float m1 = ml[r1 * 2], l1 = ml[r1 * 2 + 1];
    float M = fmaxf(m0, m1);
    float w0 = exp2f((m0 - M) * LOG2E_);
    float w1 = exp2f((m1 - M) * LOG2E_);
    float inv = 1.0f / (w0 * l0 + w1 * l1);
    const ushort* p0 = Opart + r0 * 512 + v0;
    const ushort* p1 = Opart + r1 * 512 + v0;
    ushort* po = olat + r0 * 512 + v0;
    #pragma unroll
    for (int i = 0; i < 32; i += 4) {
        ushort4 a = *(const ushort4*)(p0 + i);
        ushort4 b = *(const ushort4*)(p1 + i);
        ushort4 o;
        o.x = f2bf((w0 * bf2f(a.x) + w1 * bf2f(b.x)) * inv);
        o.y = f2bf((w0 * bf2f(a.y) + w1 * bf2f(b.y)) * inv);
        o.z = f2bf((w0 * bf2f(a.z) + w1 * bf2f(b.z)) * inv);
        o.w = f2bf((w0 * bf2f(a.w) + w1 * bf2f(b.w)) * inv);
        *(ushort4*)(po + i) = o;
    }
}

// ---------------------------------------------------------------------------
// Launch. ws footprint exactly 54,001,664 B (proven safe in R5).
// ---------------------------------------------------------------------------
extern "C" void kernel_launch(void* const* d_in, const int* in_sizes, int n_in,
                              void* d_out, int out_size, void* d_ws, size_t ws_size,
                              hipStream_t stream)
{
    const float* x    = (const float*)d_in[0];
    const float* Wq   = (const float*)d_in[1];
    const float* W_UK = (const float*)d_in[2];
    const float* W_UV = (const float*)d_in[3];
    const float* Wo   = (const float*)d_in[4];
    const float* kv_c = (const float*)d_in[5];
    const float* k_pe = (const float*)d_in[6];
    const int* topk   = (const int*)d_in[7];
    const int* pos_q  = (const int*)d_in[8];
    float* out        = (float*)d_out;

    char* wsb = (char*)d_ws;
    ushort* qb    = (ushort*)wsb;
    float*  qfull = (float*)(wsb + 4718592);
    ushort* Opart = (ushort*)(wsb + 4718592);          // overlay of qfull
    ushort* ov_b  = (ushort*)(wsb + 13107200);
    float*  ml    = (float*)(wsb + 14155776);
    ushort* olat  = qb;                                // overlay (qb dead)
    ushort* kvb   = (ushort*)(wsb + 16252928);
    if (ws_size < (size_t)54001664) return;            // fail loud, don't fault

    // 0) prep bf16 kv table (96 lanes/row)
    prep_kvb<<<12288, 256, 0, stream>>>(kv_c, k_pe, kvb);

    // 1) qfull = x @ Wq   (256 x 3072 x 2048), fp32 out
    gemm_mfma<false, false, false><<<dim3(48, 4), 256, 0, stream>>>(
        x, Wq, qfull, 256, 3072, 2048, 2048, 3072, 3072, 0, 0, 0);

    // 2) qb[:, :, 0:512] = qnope @ W_UK[h]  (256 x 512 x 128, batched over h)
    gemm_mfma<false, false, true><<<dim3(8, 4, 16), 256, 0, stream>>>(
        qfull, W_UK, qb, 256, 512, 128, 3072, 512, 9216, 192, 65536, 576);

    // 3) qb[:, :, 512:576] = bf16(rope(q_pe))
    pack_qrope<<<512, 256, 0, stream>>>(qfull, pos_q, qb);

    // 4) fused attention, split-K=2 -> partials
    mla_fused_split<<<dim3(256, 2), 256, 0, stream>>>(qb, kvb, topk, Opart, ml);

    // 5) combine partials -> olat (bf16, overlays qb)
    combine_kernel<<<256, 256, 0, stream>>>(Opart, ml, olat);

    // 6) ov_b[t, h*128+v] = olat[t,h,:] . W_UV[h,v,:]  (NT, A bf16, C bf16)
    gemm_mfma<true, true, true><<<dim3(2, 4, 16), 256, 0, stream>>>(
        olat, W_UV, ov_b, 256, 128, 512, 8192, 512, 2048, 512, 65536, 128);

    // 7) out = ov_b @ Wo   (256 x 2048 x 2048), fp32 out
    gemm_mfma<true, false, false><<<dim3(32, 4), 256, 0, stream>>>(
        ov_b, Wo, out, 256, 2048, 2048, 2048, 2048, 2048, 0, 0, 0);
}

// Round 8
// 311.560 us; speedup vs baseline: 1.8806x; 1.0366x over previous
//
#include <hip/hip_runtime.h>
#include <hip/hip_bf16.h>

// Problem constants
#define H_    16
#define NOPE_ 128
#define ROPE_ 64
#define VDIM_ 128
#define LORA_ 512
#define DM_   2048
#define T_    256
#define S_    32768
#define K_    2048

static constexpr float SCALE_ = 0.072168783648703220563643597562744f; // 1/sqrt(192)
static constexpr float LOG2E_ = 1.4426950408889634f;

typedef __attribute__((ext_vector_type(8))) short short8;   // 8 bf16 in 4 VGPRs
typedef __attribute__((ext_vector_type(4))) short short4v;  // 4 bf16 in 2 VGPRs
typedef __attribute__((ext_vector_type(4))) float f32x4;    // MFMA accumulator

__device__ __forceinline__ ushort f2bf(float f) {
    unsigned u = __float_as_uint(f);
    unsigned r = (u + 0x7FFFu + ((u >> 16) & 1u)) >> 16;    // RNE
    return (ushort)r;
}
__device__ __forceinline__ float bf2f(ushort u) {
    return __uint_as_float((unsigned)u << 16);
}

// ---------------------------------------------------------------------------
// bf16 MFMA GEMM: C[M,N] = A[M,K] @ B[K,N] (B_NT: B is [N][K] n-major).
// BM = SMALL_M ? 32 : 64, BN=64, BK=64, 256 thr.
// SMALL_M (round 8): same verified fragment/LDS layouts, waves tile 2x2 over
// 32x64 (m0=(w>>1)*16, n0=(w&1)*32, acc[1][2]) -> doubles grid for skinny
// GEMMs (GEMM1 192->384 blocks, GEMM7 128->256, GEMM6 128->256; before, up
// to half the CUs were idle).
// Register double-buffer prefetch (round 7, verified): next k-tile's global
// loads fly under the MFMA compute.
// ---------------------------------------------------------------------------
template<bool A_BF16, bool B_NT, bool C_BF16, bool SMALL_M>
__global__ __launch_bounds__(256) void gemm_mfma(
    const void* __restrict__ Av, const float* __restrict__ B, void* __restrict__ Cv,
    int M, int N, int Kd, int lda, int ldb, int ldc,
    long batchA, long batchB, long batchC)
{
    constexpr int BM = SMALL_M ? 32 : 64;
    constexpr int MT = SMALL_M ? 1 : 2;
    __shared__ ushort As[64 * 72];
    __shared__ ushort Bs[64 * 72];

    const int tid = threadIdx.x;
    const int w  = tid >> 6;
    const int l  = tid & 63;
    const int lm = l & 15;
    const int kq = l >> 4;
    const int bm = blockIdx.y * BM;
    const int bn = blockIdx.x * 64;
    const int m0 = SMALL_M ? (w >> 1) * 16 : (w >> 1) * 32;
    const int n0 = (w & 1) * 32;

    const float*  Af = A_BF16 ? nullptr : ((const float*)Av)  + (long)blockIdx.z * batchA;
    const ushort* Ah = A_BF16 ? ((const ushort*)Av) + (long)blockIdx.z * batchA : nullptr;
    B += (long)blockIdx.z * batchB;

    f32x4 acc[MT][2];
    #pragma unroll
    for (int i = 0; i < MT; ++i)
        #pragma unroll
        for (int j = 0; j < 2; ++j) acc[i][j] = (f32x4){0.f, 0.f, 0.f, 0.f};

    // staging address components
    const int am  = SMALL_M ? (tid >> 3) : (tid >> 2);           // A_BF16 row
    const int ako = SMALL_M ? (tid & 7) * 8 : (tid & 3) * 16;    // A_BF16 col
    const int amr = SMALL_M ? (tid >> 3) : (tid >> 4);           // A fp32 row
    const int akk = SMALL_M ? (tid & 7) * 8 : (tid & 15) * 4;    // A fp32 col
    const int bnr = tid >> 4, bkk = (tid & 15) * 4;              // B_NT
    const int bk  = tid >> 2, bnq = (tid & 3) * 16;              // B_NN

    // register prefetch buffers
    uint4  gA[2];
    float4 gAf[4];
    float4 gB[4];

    auto loadA = [&](int k0) {
        if constexpr (A_BF16) {
            const ushort* src = Ah + (long)(bm + am) * lda + k0 + ako;
            gA[0] = *(const uint4*)(src);
            if constexpr (!SMALL_M) gA[1] = *(const uint4*)(src + 8);
        } else {
            if constexpr (SMALL_M) {
                const float* s = Af + (long)(bm + amr) * lda + k0 + akk;
                gAf[0] = *(const float4*)s;
                gAf[1] = *(const float4*)(s + 4);
            } else {
                #pragma unroll
                for (int p = 0; p < 4; ++p)
                    gAf[p] = *(const float4*)(Af + (long)(bm + amr + p * 16) * lda + k0 + akk);
            }
        }
    };
    auto loadB = [&](int k0) {
        if constexpr (B_NT) {
            #pragma unroll
            for (int p = 0; p < 4; ++p)
                gB[p] = *(const float4*)(B + (long)(bn + bnr + p * 16) * ldb + k0 + bkk);
        } else {
            #pragma unroll
            for (int p = 0; p < 4; ++p)
                gB[p] = *(const float4*)(B + (long)(k0 + bk) * ldb + bn + bnq + p * 4);
        }
    };

    loadA(0); loadB(0);

    for (int k0 = 0; k0 < Kd; k0 += 64) {
        __syncthreads();
        // ---- store prefetched regs -> LDS (with bf16 conversion) ----
        if constexpr (A_BF16) {
            *(uint4*)(As + am * 72 + ako) = gA[0];
            if constexpr (!SMALL_M)
                *(uint4*)(As + am * 72 + ako + 8) = gA[1];
        } else {
            if constexpr (SMALL_M) {
                ushort4 u0, u1;
                u0.x = f2bf(gAf[0].x); u0.y = f2bf(gAf[0].y);
                u0.z = f2bf(gAf[0].z); u0.w = f2bf(gAf[0].w);
                u1.x = f2bf(gAf[1].x); u1.y = f2bf(gAf[1].y);
                u1.z = f2bf(gAf[1].z); u1.w = f2bf(gAf[1].w);
                *(ushort4*)(As + amr * 72 + akk)     = u0;
                *(ushort4*)(As + amr * 72 + akk + 4) = u1;
            } else {
                #pragma unroll
                for (int p = 0; p < 4; ++p) {
                    ushort4 u;
                    u.x = f2bf(gAf[p].x); u.y = f2bf(gAf[p].y);
                    u.z = f2bf(gAf[p].z); u.w = f2bf(gAf[p].w);
                    *(ushort4*)(As + (amr + p * 16) * 72 + akk) = u;
                }
            }
        }
        if constexpr (B_NT) {
            #pragma unroll
            for (int p = 0; p < 4; ++p) {
                ushort4 u;
                u.x = f2bf(gB[p].x); u.y = f2bf(gB[p].y);
                u.z = f2bf(gB[p].z); u.w = f2bf(gB[p].w);
                *(ushort4*)(Bs + (bnr + p * 16) * 72 + bkk) = u;
            }
        } else {
            #pragma unroll
            for (int p = 0; p < 4; ++p) {
                ushort4 u;
                u.x = f2bf(gB[p].x); u.y = f2bf(gB[p].y);
                u.z = f2bf(gB[p].z); u.w = f2bf(gB[p].w);
                *(ushort4*)(Bs + bk * 68 + bnq + p * 4) = u;
            }
        }
        // ---- issue next tile's loads (fly under compute) ----
        if (k0 + 64 < Kd) { loadA(k0 + 64); loadB(k0 + 64); }
        __syncthreads();
        // ---- compute: 2 k-steps of 32 ----
        #pragma unroll
        for (int ks = 0; ks < 2; ++ks) {
            short8 a[MT], b[2];
            #pragma unroll
            for (int mt = 0; mt < MT; ++mt)
                a[mt] = *(const short8*)(As + (m0 + mt * 16 + lm) * 72 + ks * 32 + kq * 8);
            if constexpr (B_NT) {
                #pragma unroll
                for (int nt = 0; nt < 2; ++nt)
                    b[nt] = *(const short8*)(Bs + (n0 + nt * 16 + lm) * 72 + ks * 32 + kq * 8);
            } else {
                #pragma unroll
                for (int nt = 0; nt < 2; ++nt)
                    #pragma unroll
                    for (int j = 0; j < 8; ++j)
                        b[nt][j] = (short)Bs[(ks * 32 + kq * 8 + j) * 68 + n0 + nt * 16 + lm];
            }
            #pragma unroll
            for (int mt = 0; mt < MT; ++mt)
                #pragma unroll
                for (int nt = 0; nt < 2; ++nt)
                    acc[mt][nt] = __builtin_amdgcn_mfma_f32_16x16x32_bf16(
                        a[mt], b[nt], acc[mt][nt], 0, 0, 0);
        }
    }
    // ---- epilogue ----
    #pragma unroll
    for (int mt = 0; mt < MT; ++mt)
        #pragma unroll
        for (int nt = 0; nt < 2; ++nt)
            #pragma unroll
            for (int r = 0; r < 4; ++r) {
                long row = bm + m0 + mt * 16 + kq * 4 + r;
                long col = bn + n0 + nt * 16 + lm;
                if constexpr (C_BF16)
                    ((ushort*)Cv)[(long)blockIdx.z * batchC + row * ldc + col] =
                        f2bf(acc[mt][nt][r]);
                else
                    ((float*)Cv)[(long)blockIdx.z * batchC + row * ldc + col] =
                        acc[mt][nt][r];
            }
}

// ---------------------------------------------------------------------------
// qb[:, :, 512:576] = bf16(rope(q_pe)) from fp32 qfull. fp64 angles.
// ---------------------------------------------------------------------------
__global__ __launch_bounds__(256) void pack_qrope(
    const float* __restrict__ qfull, const int* __restrict__ pos_q,
    ushort* __restrict__ qb)
{
    int id = blockIdx.x * 256 + threadIdx.x;     // T*H*32 = 131072
    int i = id & 31;
    int h = (id >> 5) & 15;
    int t = id >> 9;
    double inv = exp2(-(double)i * 0.41524101186092026);  // 10000^(-i/32)
    double f = (double)pos_q[t] * inv;
    double fr = f - floor(f * 0.15915494309189535) * 6.283185307179586;
    float sf, cf;
    sincosf((float)fr, &sf, &cf);
    float x1 = qfull[t * 3072 + h * 192 + 128 + i];
    float x2 = qfull[t * 3072 + h * 192 + 160 + i];
    ushort* q = qb + (long)(t * 16 + h) * 576;
    q[512 + i] = f2bf(x1 * cf - x2 * sf);
    q[544 + i] = f2bf(x2 * cf + x1 * sf);
}

// ---------------------------------------------------------------------------
// Precompute kvb[s][0:512]=bf16(kv_c[s]), kvb[s][512:576]=bf16(rope(k_pe[s],s)).
// 96 lanes/row (HW-verified round 7): 64 convert + 32 rope lanes.
// ---------------------------------------------------------------------------
__global__ __launch_bounds__(256) void prep_kvb(
    const float* __restrict__ kvc, const float* __restrict__ kpe,
    ushort* __restrict__ kvb)
{
    int id = blockIdx.x * 256 + threadIdx.x;   // 32768*96 = 3,145,728
    int s = id / 96;
    int c = id - s * 96;
    if (c < 64) {
        const float* src = kvc + (long)s * 512 + c * 8;
        float4 v0 = *(const float4*)src;
        float4 v1 = *(const float4*)(src + 4);
        ushort4 a, b;
        a.x = f2bf(v0.x); a.y = f2bf(v0.y); a.z = f2bf(v0.z); a.w = f2bf(v0.w);
        b.x = f2bf(v1.x); b.y = f2bf(v1.y); b.z = f2bf(v1.z); b.w = f2bf(v1.w);
        ushort* dst = kvb + (long)s * 576 + c * 8;
        *(ushort4*)dst = a;
        *(ushort4*)(dst + 4) = b;
    } else {
        int i = c - 64;                       // 0..31
        double inv = exp2(-(double)i * 0.41524101186092026);
        double f = (double)s * inv;
        double fr = f - floor(f * 0.15915494309189535) * 6.283185307179586;
        float sf, cf;
        sincosf((float)fr, &sf, &cf);
        const float* kp = kpe + (long)s * 64;
        float x1 = kp[i], x2 = kp[32 + i];
        ushort* dst = kvb + (long)s * 576 + 512;
        dst[i]      = f2bf(x1 * cf - x2 * sf);
        dst[32 + i] = f2bf(x2 * cf + x1 * sf);
    }
}

// ---------------------------------------------------------------------------
// Fused flash-MLA attention, split-K=2 (512 blocks, 2/CU).
//
// LDS key-tile layout, subtiled (HW-verified round 4):
//   off(s,d) = (d>>4)*2048 + (s>>2)*128 + (s&3)*32 + (d&15)*2
// ds_read_b64_tr_b16 semantics (HW-verified round 4): lane reads 8B at its
// own address; 16-lane group exchange: lane l elem j = block elem (l&15)+16j.
// global_load_lds staging (HW-verified round 6): wave w gather i fills
// d-block (w>>1)+2i for keys 32(w&1)..+31; dst = base + l*16.
//
// Round-8: PHASED gather wait (counted vmcnt). Progress guarantee: after
// every wave retires gathers 0..j, d-blocks 0..2j+1 are complete for ALL 64
// keys (even d-blocks from waves 0/1, odd from 2/3). QK step ks consumes
// d-blocks {2ks,2ks+1}. So:
//   vmcnt(12)+barrier -> QK ks 0-5   (needs d-blocks <=11, have <=11)
//   vmcnt(6) +barrier -> QK ks 6-11  (needs <=23, have <=23)
//   vmcnt(0) +barrier -> QK ks 12-17 + softmax + PV
// QK overlaps ~2/3 of gather delivery instead of stalling on vmcnt(0).
// Occupancy setup (round 7, verified): single kb buffer + launch_bounds
// (256,4) -> VGPR<=128, 2 blocks/CU, ~19% occupancy.
// ---------------------------------------------------------------------------
#define KBD 2048    // d-block pitch in bytes (16 subtiles * 128B, dense)
#define KBSZ 73728  // kb buffer (36 d-blocks)

__global__ __launch_bounds__(256, 4) void mla_fused_split(
    const ushort* __restrict__ qb, const ushort* __restrict__ kvb,
    const int* __restrict__ topk,
    ushort* __restrict__ Opart, float* __restrict__ ml)
{
    __shared__ __align__(16) char kb[KBSZ];       // 73,728 B single buffer
    __shared__ __align__(16) ushort P2[1024];     // P, key-subtiled (2 KiB)
    __shared__ float wred[2][4][16];              // [max|sum][wave][row]

    const int t = blockIdx.x;
    const int sp = blockIdx.y;          // split 0/1
    const int tid = threadIdx.x;
    const int w = tid >> 6;
    const int l = tid & 63;
    const int lm = l & 15;
    const int kq = l >> 4;

    // ---- preload Q A-fragments (18 k-steps of 32) ----
    short8 qa[18];
    {
        const ushort* qrow = qb + (long)(t * 16 + lm) * 576 + kq * 8;
        #pragma unroll
        for (int ks = 0; ks < 18; ++ks)
            qa[ks] = *(const short8*)(qrow + ks * 32);
    }

    const int* tkp = topk + (long)t * 2048 + sp * 1024;

    // staging roles (HW-verified round 6)
    const int kh   = w & 1;                    // key half (0: keys 0-31)
    const int db0  = w >> 1;                   // first d-block (step 2)
    const int skey = 32 * kh + (l >> 1);       // lane's key in tile
    const int gcol = db0 * 16 + (l & 1) * 8;   // lane's first element in row
    const unsigned stRel = (unsigned)(db0 * 2048 + kh * 1024);

    __attribute__((address_space(3))) char* kb3 =
        (__attribute__((address_space(3))) char*)&kb[0];
    const char* kbg = (const char*)&kb[0];
    const unsigned kbBase = (unsigned)(unsigned long long)(const void*)&kb[0];

    // QK B-fragment offset: key = w*16+lm, dim = ks*32 + kq*8
    const unsigned krowRel = (unsigned)((kq >> 1) * KBD + w * 512 + (lm >> 2) * 128
                     + (lm & 3) * 32 + (kq & 1) * 16);
    // PV tr-read offsets: lane lm owns the lm-th 8B chunk of each 4x16 tile
    const unsigned trb = kbBase + (unsigned)(w * 8 * KBD + kq * 256 + lm * 8);
    const unsigned ptrb = (unsigned)(unsigned long long)(const void*)P2
                        + (unsigned)(kq * 256 + lm * 8);

    f32x4 O[8];
    #pragma unroll
    for (int vt = 0; vt < 8; ++vt) O[vt] = (f32x4){0.f, 0.f, 0.f, 0.f};
    float m_r[4] = {-1e30f, -1e30f, -1e30f, -1e30f};
    float l_r[4] = {0.f, 0.f, 0.f, 0.f};

#define GSTAGE(IDX)                                                           \
    {                                                                         \
        const ushort* gs = kvb + (long)(IDX) * 576 + gcol;                    \
        _Pragma("unroll")                                                     \
        for (int i = 0; i < 18; ++i)                                          \
            __builtin_amdgcn_global_load_lds(                                 \
                (const __attribute__((address_space(1))) void*)(const void*)(gs + i * 32), \
                (__attribute__((address_space(3))) void*)(kb3 + stRel + i * 4096), \
                16, 0, 0);                                                    \
    }

    for (int tt = 0; tt < 16; ++tt) {
        int idx = tkp[tt * 64 + skey];
        __syncthreads();   // prev tile fully consumed (PV reads drained)
        GSTAGE(idx)

        const char* krow = kbg + krowRel;
        f32x4 S0 = (f32x4){0.f, 0.f, 0.f, 0.f};
        f32x4 S1 = (f32x4){0.f, 0.f, 0.f, 0.f};

        // ---- phase 1: d-blocks 0..11 landed -> QK ks 0..5 ----
        asm volatile("s_waitcnt vmcnt(12)" ::: "memory");
        __builtin_amdgcn_s_barrier();
        asm volatile("" ::: "memory");
        #pragma unroll
        for (int ks = 0; ks < 6; ks += 2) {
            short8 b0 = *(const short8*)(krow + ks * (2 * KBD));
            S0 = __builtin_amdgcn_mfma_f32_16x16x32_bf16(qa[ks], b0, S0, 0, 0, 0);
            short8 b1 = *(const short8*)(krow + (ks + 1) * (2 * KBD));
            S1 = __builtin_amdgcn_mfma_f32_16x16x32_bf16(qa[ks + 1], b1, S1, 0, 0, 0);
        }
        // ---- phase 2: d-blocks 12..23 landed -> QK ks 6..11 ----
        asm volatile("s_waitcnt vmcnt(6)" ::: "memory");
        __builtin_amdgcn_s_barrier();
        asm volatile("" ::: "memory");
        #pragma unroll
        for (int ks = 6; ks < 12; ks += 2) {
            short8 b0 = *(const short8*)(krow + ks * (2 * KBD));
            S0 = __builtin_amdgcn_mfma_f32_16x16x32_bf16(qa[ks], b0, S0, 0, 0, 0);
            short8 b1 = *(const short8*)(krow + (ks + 1) * (2 * KBD));
            S1 = __builtin_amdgcn_mfma_f32_16x16x32_bf16(qa[ks + 1], b1, S1, 0, 0, 0);
        }
        // ---- phase 3: all landed -> QK ks 12..17, then softmax/PV ----
        asm volatile("s_waitcnt vmcnt(0)" ::: "memory");
        __builtin_amdgcn_s_barrier();
        asm volatile("" ::: "memory");
        #pragma unroll
        for (int ks = 12; ks < 18; ks += 2) {
            short8 b0 = *(const short8*)(krow + ks * (2 * KBD));
            S0 = __builtin_amdgcn_mfma_f32_16x16x32_bf16(qa[ks], b0, S0, 0, 0, 0);
            short8 b1 = *(const short8*)(krow + (ks + 1) * (2 * KBD));
            S1 = __builtin_amdgcn_mfma_f32_16x16x32_bf16(qa[ks + 1], b1, S1, 0, 0, 0);
        }

        float s4[4], mx[4], p[4];
        #pragma unroll
        for (int r = 0; r < 4; ++r) { s4[r] = (S0[r] + S1[r]) * SCALE_; mx[r] = s4[r]; }
        #pragma unroll
        for (int off = 1; off < 16; off <<= 1)
            #pragma unroll
            for (int r = 0; r < 4; ++r)
                mx[r] = fmaxf(mx[r], __shfl_xor(mx[r], off, 64));
        if (lm == 0)
            #pragma unroll
            for (int r = 0; r < 4; ++r) wred[0][w][4 * kq + r] = mx[r];
        asm volatile("s_waitcnt lgkmcnt(0)" ::: "memory");
        __builtin_amdgcn_s_barrier();
        asm volatile("" ::: "memory");

        float al[4], rs[4];
        #pragma unroll
        for (int r = 0; r < 4; ++r) {
            float tm = fmaxf(fmaxf(wred[0][0][4 * kq + r], wred[0][1][4 * kq + r]),
                             fmaxf(wred[0][2][4 * kq + r], wred[0][3][4 * kq + r]));
            float mn = fmaxf(m_r[r], tm);
            al[r] = exp2f((m_r[r] - mn) * LOG2E_);
            p[r] = exp2f((s4[r] - mn) * LOG2E_);
            m_r[r] = mn;
            rs[r] = p[r];
        }
        #pragma unroll
        for (int off = 1; off < 16; off <<= 1)
            #pragma unroll
            for (int r = 0; r < 4; ++r)
                rs[r] += __shfl_xor(rs[r], off, 64);
        if (lm == 0)
            #pragma unroll
            for (int r = 0; r < 4; ++r) wred[1][w][4 * kq + r] = rs[r];
        // P write: key = w*16+lm, heads 4kq..4kq+3 consecutive -> one b64 store
        {
            ushort4 pu;
            pu.x = f2bf(p[0]); pu.y = f2bf(p[1]);
            pu.z = f2bf(p[2]); pu.w = f2bf(p[3]);
            *(ushort4*)(P2 + (w * 4 + (lm >> 2)) * 64 + (lm & 3) * 16 + 4 * kq) = pu;
        }
        #pragma unroll
        for (int vt = 0; vt < 8; ++vt)
            #pragma unroll
            for (int r = 0; r < 4; ++r)
                O[vt][r] *= al[r];
        asm volatile("s_waitcnt lgkmcnt(0)" ::: "memory");
        __builtin_amdgcn_s_barrier();
        asm volatile("" ::: "memory");   // P2 + wred[1] visible

        #pragma unroll
        for (int r = 0; r < 4; ++r) {
            float ts = wred[1][0][4 * kq + r] + wred[1][1][4 * kq + r] +
                       wred[1][2][4 * kq + r] + wred[1][3][4 * kq + r];
            l_r[r] = l_r[r] * al[r] + ts;
        }

        // ---- O += P . V : 2-slot pipelined tr reads (counted lgkmcnt) ----
        __builtin_amdgcn_sched_barrier(0);
        short4v pr[4];
        asm volatile("ds_read_b64_tr_b16 %0, %1 offset:0"    : "=v"(pr[0]) : "v"(ptrb));
        asm volatile("ds_read_b64_tr_b16 %0, %1 offset:128"  : "=v"(pr[1]) : "v"(ptrb));
        asm volatile("ds_read_b64_tr_b16 %0, %1 offset:1024" : "=v"(pr[2]) : "v"(ptrb));
        asm volatile("ds_read_b64_tr_b16 %0, %1 offset:1152" : "=v"(pr[3]) : "v"(ptrb));
        short4v rg[2][4];
#define ISSUE_V(vt, slot) \
        asm volatile("ds_read_b64_tr_b16 %0, %1 offset:%2" : "=v"(rg[slot][0]) : "v"(trb), "i"((vt) * KBD));        \
        asm volatile("ds_read_b64_tr_b16 %0, %1 offset:%2" : "=v"(rg[slot][1]) : "v"(trb), "i"((vt) * KBD + 128));  \
        asm volatile("ds_read_b64_tr_b16 %0, %1 offset:%2" : "=v"(rg[slot][2]) : "v"(trb), "i"((vt) * KBD + 1024)); \
        asm volatile("ds_read_b64_tr_b16 %0, %1 offset:%2" : "=v"(rg[slot][3]) : "v"(trb), "i"((vt) * KBD + 1152));
        ISSUE_V(0, 0)
        ISSUE_V(1, 1)
        asm volatile("s_waitcnt lgkmcnt(8)" ::: "memory");   // pr ready
        __builtin_amdgcn_sched_barrier(0);
        short8 pa0 = __builtin_shufflevector(pr[0], pr[1], 0, 1, 2, 3, 4, 5, 6, 7);
        short8 pa1 = __builtin_shufflevector(pr[2], pr[3], 0, 1, 2, 3, 4, 5, 6, 7);
        #pragma unroll
        for (int vt = 0; vt < 8; ++vt) {
            if (vt < 7)
                asm volatile("s_waitcnt lgkmcnt(4)" ::: "memory");  // chunk vt ready
            else
                asm volatile("s_waitcnt lgkmcnt(0)" ::: "memory");
            __builtin_amdgcn_sched_barrier(0);
            short8 bv0 = __builtin_shufflevector(rg[vt & 1][0], rg[vt & 1][1],
                                                 0, 1, 2, 3, 4, 5, 6, 7);
            O[vt] = __builtin_amdgcn_mfma_f32_16x16x32_bf16(pa0, bv0, O[vt], 0, 0, 0);
            short8 bv1 = __builtin_shufflevector(rg[vt & 1][2], rg[vt & 1][3],
                                                 0, 1, 2, 3, 4, 5, 6, 7);
            O[vt] = __builtin_amdgcn_mfma_f32_16x16x32_bf16(pa1, bv1, O[vt], 0, 0, 0);
            if (vt < 6) { ISSUE_V(vt + 2, vt & 1) }   // slot now free
        }
#undef ISSUE_V
    }

    // ---- epilogue: store unnormalized partial O (bf16) + (m,l) ----
    const long rbase = ((long)sp * 256 + t) * 16;
    #pragma unroll
    for (int vt = 0; vt < 8; ++vt)
        #pragma unroll
        for (int r = 0; r < 4; ++r)
            Opart[(rbase + 4 * kq + r) * 512 + w * 128 + vt * 16 + lm] = f2bf(O[vt][r]);
    if (w == 0 && lm == 0) {
        #pragma unroll
        for (int r = 0; r < 4; ++r) {
            ml[(rbase + 4 * kq + r) * 2 + 0] = m_r[r];
            ml[(rbase + 4 * kq + r) * 2 + 1] = l_r[r];
        }
    }
#undef GSTAGE
}

// ---------------------------------------------------------------------------
// Merge the 2 split-K partials -> olat bf16.
// ---------------------------------------------------------------------------
__global__ __launch_bounds__(256) void combine_kernel(
    const ushort* __restrict__ Opart, const float* __restrict__ ml,
    ushort* __restrict__ olat)
{
    const int t = blockIdx.x;
    const int h = threadIdx.x >> 4;
    const int v0 = (threadIdx.x & 15) * 32;
    const long r0 = (long)t * 16 + h;
    const long r1 = (long)(256 + t) * 16 + h;
    float m0 = ml[r0 * 2], l0 = ml[r0 * 2 + 1];
    float m1 = ml[r1 * 2], l1 = ml[r1 * 2 + 1];
    float M = fmaxf(m0, m1);
    float w0 = exp2f((m0 - M) * LOG2E_);
    float w1 = exp2f((m1 - M) * LOG2E_);
    float inv = 1.0f / (w0 * l0 + w1 * l1);
    const ushort* p0 = Opart + r0 * 512 + v0;
    const ushort* p1 = Opart + r1 * 512 + v0;
    ushort* po = olat + r0 * 512 + v0;
    #pragma unroll
    for (int i = 0; i < 32; i += 4) {
        ushort4 a = *(const ushort4*)(p0 + i);
        ushort4 b = *(const ushort4*)(p1 + i);
        ushort4 o;
        o.x = f2bf((w0 * bf2f(a.x) + w1 * bf2f(b.x)) * inv);
        o.y = f2bf((w0 * bf2f(a.y) + w1 * bf2f(b.y)) * inv);
        o.z = f2bf((w0 * bf2f(a.z) + w1 * bf2f(b.z)) * inv);
        o.w = f2bf((w0 * bf2f(a.w) + w1 * bf2f(b.w)) * inv);
        *(ushort4*)(po + i) = o;
    }
}

// ---------------------------------------------------------------------------
// Launch. ws footprint exactly 54,001,664 B (proven safe in R5).
// ---------------------------------------------------------------------------
extern "C" void kernel_launch(void* const* d_in, const int* in_sizes, int n_in,
                              void* d_out, int out_size, void* d_ws, size_t ws_size,
                              hipStream_t stream)
{
    const float* x    = (const float*)d_in[0];
    const float* Wq   = (const float*)d_in[1];
    const float* W_UK = (const float*)d_in[2];
    const float* W_UV = (const float*)d_in[3];
    const float* Wo   = (const float*)d_in[4];
    const float* kv_c = (const float*)d_in[5];
    const float* k_pe = (const float*)d_in[6];
    const int* topk   = (const int*)d_in[7];
    const int* pos_q  = (const int*)d_in[8];
    float* out        = (float*)d_out;

    char* wsb = (char*)d_ws;
    ushort* qb    = (ushort*)wsb;
    float*  qfull = (float*)(wsb + 4718592);
    ushort* Opart = (ushort*)(wsb + 4718592);          // overlay of qfull
    ushort* ov_b  = (ushort*)(wsb + 13107200);
    float*  ml    = (float*)(wsb + 14155776);
    ushort* olat  = qb;                                // overlay (qb dead)
    ushort* kvb   = (ushort*)(wsb + 16252928);
    if (ws_size < (size_t)54001664) return;            // fail loud, don't fault

    // 0) prep bf16 kv table (96 lanes/row)
    prep_kvb<<<12288, 256, 0, stream>>>(kv_c, k_pe, kvb);

    // 1) qfull = x @ Wq   (256 x 3072 x 2048), fp32 out — BM=32, 384 blocks
    gemm_mfma<false, false, false, true><<<dim3(48, 8), 256, 0, stream>>>(
        x, Wq, qfull, 256, 3072, 2048, 2048, 3072, 3072, 0, 0, 0);

    // 2) qb[:, :, 0:512] = qnope @ W_UK[h]  (256 x 512 x 128, batched over h)
    gemm_mfma<false, false, true, false><<<dim3(8, 4, 16), 256, 0, stream>>>(
        qfull, W_UK, qb, 256, 512, 128, 3072, 512, 9216, 192, 65536, 576);

    // 3) qb[:, :, 512:576] = bf16(rope(q_pe))
    pack_qrope<<<512, 256, 0, stream>>>(qfull, pos_q, qb);

    // 4) fused attention, split-K=2 -> partials
    mla_fused_split<<<dim3(256, 2), 256, 0, stream>>>(qb, kvb, topk, Opart, ml);

    // 5) combine partials -> olat (bf16, overlays qb)
    combine_kernel<<<256, 256, 0, stream>>>(Opart, ml, olat);

    // 6) ov_b = olat @ W_UV (NT, batched) — BM=32, 256 blocks
    gemm_mfma<true, true, true, true><<<dim3(2, 8, 16), 256, 0, stream>>>(
        olat, W_UV, ov_b, 256, 128, 512, 8192, 512, 2048, 512, 65536, 128);

    // 7) out = ov_b @ Wo   (256 x 2048 x 2048), fp32 out — BM=32, 256 blocks
    gemm_mfma<true, false, false, true><<<dim3(32, 8), 256, 0, stream>>>(
        ov_b, Wo, out, 256, 2048, 2048, 2048, 2048, 2048, 0, 0, 0);
}